// Round 4
// baseline (18433.992 us; speedup 1.0000x reference)
//
#include <hip/hip_runtime.h>
#include <math.h>

#define SQ   4096
#define EDIM 512
#define CEDIM 128
#define CHH  128
#define WH   512
#define NT   50
#define NWGW 16

__device__ __forceinline__ float sigf(float x) { return 1.0f / (1.0f + expf(-x)); }

// Named-register weight hold. The empty asm makes each loaded value opaque
// (cannot be rematerialized from memory), forcing it to stay in VGPRs.
#define WLOAD(n) \
  float4 w##n = wp[n]; \
  asm volatile("" : "+v"(w##n.x), "+v"(w##n.y), "+v"(w##n.z), "+v"(w##n.w));
#define WLOAD_ALL \
  WLOAD(0) WLOAD(1) WLOAD(2) WLOAD(3) WLOAD(4) WLOAD(5) WLOAD(6) WLOAD(7) \
  WLOAD(8) WLOAD(9) WLOAD(10) WLOAD(11) WLOAD(12) WLOAD(13) WLOAD(14) WLOAD(15) \
  WLOAD(16) WLOAD(17) WLOAD(18) WLOAD(19) WLOAD(20) WLOAD(21) WLOAD(22) WLOAD(23) \
  WLOAD(24) WLOAD(25) WLOAD(26) WLOAD(27) WLOAD(28) WLOAD(29) WLOAD(30) WLOAD(31)
#define WDOT(n) \
  a0 += w##n.x * hs[4*n+0]; a1 += w##n.y * hs[4*n+1]; \
  a2 += w##n.z * hs[4*n+2]; a3 += w##n.w * hs[4*n+3];
#define WDOT_ALL \
  WDOT(0) WDOT(1) WDOT(2) WDOT(3) WDOT(4) WDOT(5) WDOT(6) WDOT(7) \
  WDOT(8) WDOT(9) WDOT(10) WDOT(11) WDOT(12) WDOT(13) WDOT(14) WDOT(15) \
  WDOT(16) WDOT(17) WDOT(18) WDOT(19) WDOT(20) WDOT(21) WDOT(22) WDOT(23) \
  WDOT(24) WDOT(25) WDOT(26) WDOT(27) WDOT(28) WDOT(29) WDOT(30) WDOT(31)

// ---------------------------------------------------------------------------
// K1: gather word/char embedding rows; compute char-LSTM input GEMM
// ---------------------------------------------------------------------------
__global__ __launch_bounds__(256) void k1_gather_cgx(
    const int* __restrict__ sent, const int* __restrict__ csent,
    const float* __restrict__ wemb, const float* __restrict__ cemb,
    const float* __restrict__ cWih_f, const float* __restrict__ cb_f,
    const float* __restrict__ cWih_b, const float* __restrict__ cb_b,
    float* __restrict__ we_g, float* __restrict__ cgx)
{
    const int tid = threadIdx.x;
    const int t0 = blockIdx.x * 16;
    __shared__ __align__(16) float ceL[16][128];
    __shared__ int sids[16], cids[16];
    if (tid < 16) sids[tid] = sent[t0 + tid];
    else if (tid < 32) cids[tid - 16] = csent[t0 + tid - 16];
    __syncthreads();
    {
        int f4 = tid;
        for (int q = 0; q < 2; ++q, f4 += 256) {
            int r = f4 >> 5, k4 = f4 & 31;
            float4 v = *(const float4*)&cemb[(size_t)cids[r] * CEDIM + k4 * 4];
            *(float4*)&ceL[r][k4 * 4] = v;
        }
    }
    {
        int f4 = tid;
        for (int q = 0; q < 8; ++q, f4 += 256) {
            int r = f4 >> 7, k4 = f4 & 127;
            float4 v = *(const float4*)&wemb[(size_t)sids[r] * EDIM + k4 * 4];
            *(float4*)&we_g[(size_t)(t0 + r) * EDIM + k4 * 4] = v;
        }
    }
    __syncthreads();
    for (int q = 0; q < 4; ++q) {
        int j = q * 256 + tid;
        int d = j >> 9, r = j & 511;
        const float* Wih = d ? cWih_b : cWih_f;
        const float* cb = d ? cb_b : cb_f;
        float b = cb[r];
        float acc[16];
#pragma unroll
        for (int tt = 0; tt < 16; ++tt) acc[tt] = b;
        for (int k4 = 0; k4 < 32; ++k4) {
            float4 wv = *(const float4*)&Wih[r * CEDIM + k4 * 4];
#pragma unroll
            for (int tt = 0; tt < 16; ++tt) {
                acc[tt] += wv.x * ceL[tt][k4 * 4 + 0] + wv.y * ceL[tt][k4 * 4 + 1]
                         + wv.z * ceL[tt][k4 * 4 + 2] + wv.w * ceL[tt][k4 * 4 + 3];
            }
        }
#pragma unroll
        for (int tt = 0; tt < 16; ++tt)
            cgx[((size_t)d * SQ + (t0 + tt)) * 512 + r] = acc[tt];
    }
}

// ---------------------------------------------------------------------------
// K2: blocks 0,1 = char BiLSTM (weights pinned in registers); blocks 2+ = GEMM
// ---------------------------------------------------------------------------
__global__ __launch_bounds__(512, 2) void k2_charlstm_gemm(
    const float* __restrict__ cWhh_f, const float* __restrict__ cWhh_b,
    const float* __restrict__ cgx, float* __restrict__ cho,
    const float* __restrict__ we_g,
    const float* __restrict__ wWih_f, const float* __restrict__ wb_f,
    const float* __restrict__ wWih_b, const float* __restrict__ wb_b,
    float* __restrict__ wgx)
{
    const int tid = threadIdx.x;
    __shared__ __align__(16) float At[32][68];
    __shared__ __align__(16) float Bt[32][128];
    __shared__ __align__(16) float hb[128];
    __shared__ __align__(16) float gb[512];

    if (blockIdx.x < 2) {
        const int dir = blockIdx.x;
        const float* Whh = dir ? cWhh_b : cWhh_f;
        const int row = tid;               // gate*128 + unit
        const float4* wp = (const float4*)&Whh[(size_t)row * CHH];
        WLOAD_ALL
        const float* gx = cgx + (size_t)dir * SQ * 512;
        float cst = 0.0f;
        if (tid < 32) *(float4*)&hb[tid * 4] = make_float4(0, 0, 0, 0);
        __syncthreads();
        for (int t = 0; t < SQ; ++t) {
            const int x = dir ? (SQ - 1 - t) : t;
            float gxv = gx[(size_t)x * 512 + row];
            const float* hs = hb;
            float a0 = 0.f, a1 = 0.f, a2 = 0.f, a3 = 0.f;
            WDOT_ALL
            gb[row] = (a0 + a1) + (a2 + a3) + gxv;
            __syncthreads();
            if (tid < 128) {
                float iv = gb[tid], fv = gb[128 + tid], gv = gb[256 + tid], ov = gb[384 + tid];
                cst = sigf(fv) * cst + sigf(iv) * tanhf(gv);
                float h = sigf(ov) * tanhf(cst);
                hb[tid] = h;
                cho[(size_t)x * 256 + dir * CHH + tid] = h;
            }
            __syncthreads();
        }
        return;
    }
    // ---------------- GEMM (word-emb part of word gx) ----------------
    const int tile = blockIdx.x - 2;
    const int dir = tile >> 10;
    const int rem = tile & 1023;
    const int mb = rem >> 4;
    const int nb = rem & 15;
    const float* Wih = dir ? wWih_b : wWih_f;
    const float* wb = dir ? wb_b : wb_f;
    float* C = wgx + (size_t)dir * SQ * 2048;
    const int tm = tid >> 5, tn = tid & 31;
    float acc[4][4];
#pragma unroll
    for (int i = 0; i < 4; ++i)
#pragma unroll
        for (int jj = 0; jj < 4; ++jj) acc[i][jj] = 0.f;
    for (int kb = 0; kb < 16; ++kb) {
        {
            int rowm = tid >> 3, k4 = tid & 7;
            float4 v = *(const float4*)&we_g[(size_t)(mb * 64 + rowm) * EDIM + kb * 32 + k4 * 4];
            At[k4 * 4 + 0][rowm] = v.x; At[k4 * 4 + 1][rowm] = v.y;
            At[k4 * 4 + 2][rowm] = v.z; At[k4 * 4 + 3][rowm] = v.w;
        }
#pragma unroll
        for (int q = 0; q < 2; ++q) {
            int f4 = q * 512 + tid;
            int rr = f4 >> 3, k4 = f4 & 7;
            float4 v = *(const float4*)&Wih[(size_t)(nb * 128 + rr) * 768 + kb * 32 + k4 * 4];
            Bt[k4 * 4 + 0][rr] = v.x; Bt[k4 * 4 + 1][rr] = v.y;
            Bt[k4 * 4 + 2][rr] = v.z; Bt[k4 * 4 + 3][rr] = v.w;
        }
        __syncthreads();
#pragma unroll
        for (int kk = 0; kk < 32; ++kk) {
            float4 a4 = *(const float4*)&At[kk][tm * 4];
            float4 b4 = *(const float4*)&Bt[kk][tn * 4];
            acc[0][0] += a4.x * b4.x; acc[0][1] += a4.x * b4.y; acc[0][2] += a4.x * b4.z; acc[0][3] += a4.x * b4.w;
            acc[1][0] += a4.y * b4.x; acc[1][1] += a4.y * b4.y; acc[1][2] += a4.y * b4.z; acc[1][3] += a4.y * b4.w;
            acc[2][0] += a4.z * b4.x; acc[2][1] += a4.z * b4.y; acc[2][2] += a4.z * b4.z; acc[2][3] += a4.z * b4.w;
            acc[3][0] += a4.w * b4.x; acc[3][1] += a4.w * b4.y; acc[3][2] += a4.w * b4.z; acc[3][3] += a4.w * b4.w;
        }
        __syncthreads();
    }
    float4 wbv = *(const float4*)&wb[nb * 128 + tn * 4];
#pragma unroll
    for (int i = 0; i < 4; ++i) {
        float4 o;
        o.x = acc[i][0] + wbv.x; o.y = acc[i][1] + wbv.y;
        o.z = acc[i][2] + wbv.z; o.w = acc[i][3] + wbv.w;
        *(float4*)&C[(size_t)(mb * 64 + tm * 4 + i) * 2048 + nb * 128 + tn * 4] = o;
    }
}

// ---------------------------------------------------------------------------
// K3: wgx += char_out . wWih[:,512:768]^T
// ---------------------------------------------------------------------------
__global__ __launch_bounds__(512, 2) void k3_gemm_char(
    const float* __restrict__ cho,
    const float* __restrict__ wWih_f, const float* __restrict__ wWih_b,
    float* __restrict__ wgx)
{
    const int tid = threadIdx.x;
    const int tile = blockIdx.x;
    const int dir = tile >> 10;
    const int rem = tile & 1023;
    const int mb = rem >> 4, nb = rem & 15;
    const float* Wih = dir ? wWih_b : wWih_f;
    float* C = wgx + (size_t)dir * SQ * 2048;
    __shared__ __align__(16) float At[32][68];
    __shared__ __align__(16) float Bt[32][128];
    const int tm = tid >> 5, tn = tid & 31;
    float acc[4][4];
#pragma unroll
    for (int i = 0; i < 4; ++i)
#pragma unroll
        for (int jj = 0; jj < 4; ++jj) acc[i][jj] = 0.f;
    for (int kb = 0; kb < 8; ++kb) {
        {
            int rowm = tid >> 3, k4 = tid & 7;
            float4 v = *(const float4*)&cho[(size_t)(mb * 64 + rowm) * 256 + kb * 32 + k4 * 4];
            At[k4 * 4 + 0][rowm] = v.x; At[k4 * 4 + 1][rowm] = v.y;
            At[k4 * 4 + 2][rowm] = v.z; At[k4 * 4 + 3][rowm] = v.w;
        }
#pragma unroll
        for (int q = 0; q < 2; ++q) {
            int f4 = q * 512 + tid;
            int rr = f4 >> 3, k4 = f4 & 7;
            float4 v = *(const float4*)&Wih[(size_t)(nb * 128 + rr) * 768 + 512 + kb * 32 + k4 * 4];
            Bt[k4 * 4 + 0][rr] = v.x; Bt[k4 * 4 + 1][rr] = v.y;
            Bt[k4 * 4 + 2][rr] = v.z; Bt[k4 * 4 + 3][rr] = v.w;
        }
        __syncthreads();
#pragma unroll
        for (int kk = 0; kk < 32; ++kk) {
            float4 a4 = *(const float4*)&At[kk][tm * 4];
            float4 b4 = *(const float4*)&Bt[kk][tn * 4];
            acc[0][0] += a4.x * b4.x; acc[0][1] += a4.x * b4.y; acc[0][2] += a4.x * b4.z; acc[0][3] += a4.x * b4.w;
            acc[1][0] += a4.y * b4.x; acc[1][1] += a4.y * b4.y; acc[1][2] += a4.y * b4.z; acc[1][3] += a4.y * b4.w;
            acc[2][0] += a4.z * b4.x; acc[2][1] += a4.z * b4.y; acc[2][2] += a4.z * b4.z; acc[2][3] += a4.z * b4.w;
            acc[3][0] += a4.w * b4.x; acc[3][1] += a4.w * b4.y; acc[3][2] += a4.w * b4.z; acc[3][3] += a4.w * b4.w;
        }
        __syncthreads();
    }
#pragma unroll
    for (int i = 0; i < 4; ++i) {
        float* cp = &C[(size_t)(mb * 64 + tm * 4 + i) * 2048 + nb * 128 + tn * 4];
        float4 o = *(float4*)cp;
        o.x += acc[i][0]; o.y += acc[i][1]; o.z += acc[i][2]; o.w += acc[i][3];
        *(float4*)cp = o;
    }
}

// ---------------------------------------------------------------------------
// K4: word BiLSTM, 16 persistent WGs/direction. Weights pinned in VGPRs;
//     h exchange via sc0|sc1 (L1+L2 bypass) loads; relaxed flags; vmcnt drain
//     orders h-store before flag release.
// ---------------------------------------------------------------------------
__global__ __launch_bounds__(512, 2) void k4_word_lstm(
    const float* __restrict__ wWhh_f, const float* __restrict__ wWhh_b,
    const float* __restrict__ wgx, float* __restrict__ lstm, int* __restrict__ ctr)
{
    const int res = blockIdx.x & 7;
    if (res > 1) return;
    const int dir = res;
    const int wid = blockIdx.x >> 3;     // 0..15
    const int tid = threadIdx.x;
    const float* Whh = dir ? wWhh_b : wWhh_f;
    const int p = tid >> 2, c = tid & 3;
    const int j = p & 31, g = p >> 5;
    const int ub = wid * 32;
    const int row = g * WH + ub + j;
    const float4* wp = (const float4*)&Whh[(size_t)row * WH + c * 128];
    WLOAD_ALL
    __shared__ __align__(16) float hb[544];   // 4 chunks of 128, stride 132
    __shared__ __align__(16) float gbuf[128];
    const float* gx = wgx + (size_t)dir * SQ * 2048;
    int* myctr = ctr + dir * SQ;
    float cst = 0.0f;
    for (int t = 0; t < SQ; ++t) {
        const int x = dir ? (SQ - 1 - t) : t;
        // prefetch gate inputs (independent of h) before the flag wait
        float gxi = 0.f, gxf = 0.f, gxg = 0.f, gxo = 0.f;
        if (tid < 32) {
            const size_t gbase = (size_t)x * 2048 + ub + tid;
            gxi = gx[gbase]; gxf = gx[gbase + 512];
            gxg = gx[gbase + 1024]; gxo = gx[gbase + 1536];
        }
        if (t == 0) {
            if (tid < 128) {
                int pb = tid * 4 + (tid >> 5) * 4;
                hb[pb] = 0.f; hb[pb + 1] = 0.f; hb[pb + 2] = 0.f; hb[pb + 3] = 0.f;
            }
        } else {
            if (tid == 0) {
                while (__hip_atomic_load(&myctr[t - 1], __ATOMIC_RELAXED, __HIP_MEMORY_SCOPE_AGENT) < NWGW)
                    __builtin_amdgcn_s_sleep(1);
            }
            __syncthreads();
            const int xp = dir ? (x + 1) : (x - 1);
            if (tid < 128) {
                const float* hp = &lstm[(size_t)xp * 1024 + dir * WH + tid * 4];
                float4 hv;
                asm volatile("global_load_dwordx4 %0, %1, off sc0 sc1"
                             : "=v"(hv) : "v"(hp) : "memory");
                asm volatile("s_waitcnt vmcnt(0)" ::: "memory");
                int pb = tid * 4 + (tid >> 5) * 4;
                hb[pb] = hv.x; hb[pb + 1] = hv.y; hb[pb + 2] = hv.z; hb[pb + 3] = hv.w;
            }
        }
        __syncthreads();
        const float* hs = &hb[c * 132];
        float a0 = 0.f, a1 = 0.f, a2 = 0.f, a3 = 0.f;
        WDOT_ALL
        float acc = (a0 + a1) + (a2 + a3);
        acc += __shfl_xor(acc, 1);
        acc += __shfl_xor(acc, 2);
        if (c == 0) gbuf[p] = acc;
        __syncthreads();
        if (tid < 32) {
            const int rb = ub + tid;
            float iv = gbuf[tid]      + gxi;
            float fv = gbuf[32 + tid] + gxf;
            float gv = gbuf[64 + tid] + gxg;
            float ov = gbuf[96 + tid] + gxo;
            cst = sigf(fv) * cst + sigf(iv) * tanhf(gv);
            float h = sigf(ov) * tanhf(cst);
            __hip_atomic_store(&lstm[(size_t)x * 1024 + dir * WH + rb], h,
                               __ATOMIC_RELAXED, __HIP_MEMORY_SCOPE_AGENT);
            asm volatile("s_waitcnt vmcnt(0)" ::: "memory");
            if (tid == 0)
                __hip_atomic_fetch_add(&myctr[t], 1, __ATOMIC_RELAXED, __HIP_MEMORY_SCOPE_AGENT);
        }
    }
}

// ---------------------------------------------------------------------------
// K5: emissions = lstm_out @ W_tag^T + b_tag
// ---------------------------------------------------------------------------
__global__ __launch_bounds__(64) void k5_emis(
    const float* __restrict__ lstm, const float* __restrict__ Wtag,
    const float* __restrict__ btag, float* __restrict__ emis)
{
    const int t = blockIdx.x, tid = threadIdx.x;
    __shared__ __align__(16) float rowL[1024];
#pragma unroll
    for (int q = 0; q < 4; ++q) {
        int f4 = q * 64 + tid;
        *(float4*)&rowL[f4 * 4] = *(const float4*)&lstm[(size_t)t * 1024 + f4 * 4];
    }
    __syncthreads();
    if (tid < NT) {
        float a0 = 0.f, a1 = 0.f, a2 = 0.f, a3 = 0.f;
        const float* wr = Wtag + (size_t)tid * 1024;
        for (int k4 = 0; k4 < 256; ++k4) {
            float4 wv = *(const float4*)&wr[k4 * 4];
            a0 += wv.x * rowL[k4 * 4 + 0];
            a1 += wv.y * rowL[k4 * 4 + 1];
            a2 += wv.z * rowL[k4 * 4 + 2];
            a3 += wv.w * rowL[k4 * 4 + 3];
        }
        emis[(size_t)t * NT + tid] = btag[tid] + (a0 + a1) + (a2 + a3);
    }
}

// ---------------------------------------------------------------------------
// K6a: Viterbi forward (sequential)
// ---------------------------------------------------------------------------
__global__ __launch_bounds__(256) void k6a_viterbi(
    const float* __restrict__ emis, const float* __restrict__ start_t,
    const float* __restrict__ end_t, const float* __restrict__ trans,
    unsigned char* __restrict__ bpb, int* __restrict__ last)
{
    const int tid = threadIdx.x;
    const int g = tid >> 6, c = tid & 63;
    __shared__ float sc[64];
    __shared__ float pbest[4][64];
    __shared__ int pbp[4][64];
    const int p0 = g * 13;
    float tr[13];
#pragma unroll
    for (int i = 0; i < 13; ++i) {
        int p = p0 + i;
        tr[i] = (c < NT && p < NT) ? trans[p * NT + c] : -1e30f;
    }
    if (tid < 64) sc[tid] = (tid < NT) ? (start_t[tid] + emis[tid]) : -1e30f;
    __syncthreads();
    for (int t = 1; t < SQ; ++t) {
        float best = -1e30f; int bp = 0;
#pragma unroll
        for (int i = 0; i < 13; ++i) {
            float v = sc[p0 + i] + tr[i];
            if (v > best) { best = v; bp = p0 + i; }
        }
        pbest[g][c] = best; pbp[g][c] = bp;
        __syncthreads();
        if (tid < NT) {
            float b = pbest[0][tid]; int bb = pbp[0][tid];
#pragma unroll
            for (int gg = 1; gg < 4; ++gg) {
                float v = pbest[gg][tid];
                if (v > b) { b = v; bb = pbp[gg][tid]; }
            }
            bpb[(size_t)t * NT + tid] = (unsigned char)bb;
            sc[tid] = b + emis[(size_t)t * NT + tid];
        }
        __syncthreads();
    }
    if (tid == 0) {
        float b = -1e30f; int bi = 0;
        for (int cc = 0; cc < NT; ++cc) {
            float v = sc[cc] + end_t[cc];
            if (v > b) { b = v; bi = cc; }
        }
        *last = bi;
    }
}

// K6b: per-chunk end-tag -> end-of-previous-chunk-tag maps
__global__ __launch_bounds__(64) void k6b_maps(
    const unsigned char* __restrict__ bpb, int* __restrict__ map_)
{
    const int k = blockIdx.x;
    const int e = threadIdx.x;
    if (k == 0 || e >= NT) return;
    int tag = e;
    for (int i = 63; i >= 0; --i) {
        int t = k * 64 + i;
        tag = bpb[(size_t)t * NT + tag];
    }
    map_[k * NT + e] = tag;
}

// K6c: stitch chunk boundary tags, emit path
__global__ __launch_bounds__(64) void k6c_backtrack(
    const unsigned char* __restrict__ bpb, const int* __restrict__ map_,
    const int* __restrict__ last, int* __restrict__ path)
{
    __shared__ int B[64];
    if (threadIdx.x == 0) {
        int tag = *last;
        B[63] = tag;
        for (int k = 63; k >= 1; --k) {
            tag = map_[k * NT + tag];
            B[k - 1] = tag;
        }
    }
    __syncthreads();
    const int k = threadIdx.x;
    int tag = B[k];
    for (int i = 63; i >= 0; --i) {
        int t = k * 64 + i;
        path[t] = tag;
        if (t >= 1) tag = bpb[(size_t)t * NT + tag];
    }
}

// ---------------------------------------------------------------------------
extern "C" void kernel_launch(void* const* d_in, const int* in_sizes, int n_in,
                              void* d_out, int out_size, void* d_ws, size_t ws_size,
                              hipStream_t stream)
{
    const int* sent = (const int*)d_in[0];
    const int* csent = (const int*)d_in[1];
    const float* wemb = (const float*)d_in[2];
    const float* cemb = (const float*)d_in[3];
    const float* cWih_f = (const float*)d_in[4];
    const float* cWhh_f = (const float*)d_in[5];
    const float* cb_f = (const float*)d_in[6];
    const float* cWih_b = (const float*)d_in[7];
    const float* cWhh_b = (const float*)d_in[8];
    const float* cb_b = (const float*)d_in[9];
    const float* wWih_f = (const float*)d_in[10];
    const float* wWhh_f = (const float*)d_in[11];
    const float* wb_f = (const float*)d_in[12];
    const float* wWih_b = (const float*)d_in[13];
    const float* wWhh_b = (const float*)d_in[14];
    const float* wb_b = (const float*)d_in[15];
    const float* Wtag = (const float*)d_in[16];
    const float* btag = (const float*)d_in[17];
    const float* start_t = (const float*)d_in[18];
    const float* end_t = (const float*)d_in[19];
    const float* trans = (const float*)d_in[20];
    int* path = (int*)d_out;

    float* ws = (float*)d_ws;
    float* we_g = ws;                                   // SQ*EDIM
    float* cgx  = we_g + (size_t)SQ * EDIM;             // 2*SQ*512
    float* cho  = cgx + (size_t)2 * SQ * 512;           // SQ*256
    float* wgx  = cho + (size_t)SQ * 256;               // 2*SQ*2048
    float* lstm = wgx + (size_t)2 * SQ * 2048;          // SQ*1024
    float* emis = lstm + (size_t)SQ * 1024;             // SQ*NT
    int* ctr    = (int*)(emis + (size_t)SQ * NT);       // 2*SQ
    int* map_   = ctr + 2 * SQ;                         // 64*NT
    int* lastp  = map_ + 64 * NT;                       // 1 (+pad)
    unsigned char* bpb = (unsigned char*)(lastp + 4);   // SQ*NT bytes

    hipMemsetAsync(ctr, 0, 2 * SQ * sizeof(int), stream);

    k1_gather_cgx<<<SQ / 16, 256, 0, stream>>>(sent, csent, wemb, cemb,
                                               cWih_f, cb_f, cWih_b, cb_b, we_g, cgx);
    k2_charlstm_gemm<<<2 + 2048, 512, 0, stream>>>(cWhh_f, cWhh_b, cgx, cho, we_g,
                                                   wWih_f, wb_f, wWih_b, wb_b, wgx);
    k3_gemm_char<<<2048, 512, 0, stream>>>(cho, wWih_f, wWih_b, wgx);
    k4_word_lstm<<<128, 512, 0, stream>>>(wWhh_f, wWhh_b, wgx, lstm, ctr);
    k5_emis<<<SQ, 64, 0, stream>>>(lstm, Wtag, btag, emis);
    k6a_viterbi<<<1, 256, 0, stream>>>(emis, start_t, end_t, trans, bpb, lastp);
    k6b_maps<<<64, 64, 0, stream>>>(bpb, map_);
    k6c_backtrack<<<1, 64, 0, stream>>>(bpb, map_, lastp, path);
}

// Round 9
// 18364.661 us; speedup vs baseline: 1.0038x; 1.0038x over previous
//
#include <hip/hip_runtime.h>
#include <math.h>

#define SQ   4096
#define EDIM 512
#define CEDIM 128
#define CHH  128
#define WH   512
#define NT   50

__device__ __forceinline__ float sigf(float x) { return 1.0f / (1.0f + expf(-x)); }

#define PIN4(V) asm volatile("" : "+v"(V.x), "+v"(V.y), "+v"(V.z), "+v"(V.w));

// proven-coherent helpers: relaxed agent-scope atomics (round 2-4 recipe)
__device__ __forceinline__ int ld_flag(const int* p) {
    return __hip_atomic_load(p, __ATOMIC_RELAXED, __HIP_MEMORY_SCOPE_AGENT);
}
__device__ __forceinline__ void st_flag(int* p, int v) {
    __hip_atomic_store(p, v, __ATOMIC_RELAXED, __HIP_MEMORY_SCOPE_AGENT);
}
__device__ __forceinline__ void ld_h2(const float* p, float* dst) {
    unsigned long long q = __hip_atomic_load((const unsigned long long*)p,
                                             __ATOMIC_RELAXED, __HIP_MEMORY_SCOPE_AGENT);
    union { unsigned long long q; float f[2]; } cv; cv.q = q;
    dst[0] = cv.f[0]; dst[1] = cv.f[1];
}
__device__ __forceinline__ void st_h(float* p, float v) {
    __hip_atomic_store(p, v, __ATOMIC_RELAXED, __HIP_MEMORY_SCOPE_AGENT);
}

#define FMA4(W, off) { float4 h4 = *(const float4*)&hc[off]; \
    a0 += W.x * h4.x; a1 += W.y * h4.y; a2 += W.z * h4.z; a3 += W.w * h4.w; }

// ---------------------------------------------------------------------------
// K1: gather word/char embedding rows; compute char-LSTM input GEMM
// ---------------------------------------------------------------------------
__global__ __launch_bounds__(256) void k1_gather_cgx(
    const int* __restrict__ sent, const int* __restrict__ csent,
    const float* __restrict__ wemb, const float* __restrict__ cemb,
    const float* __restrict__ cWih_f, const float* __restrict__ cb_f,
    const float* __restrict__ cWih_b, const float* __restrict__ cb_b,
    float* __restrict__ we_g, float* __restrict__ cgx)
{
    const int tid = threadIdx.x;
    const int t0 = blockIdx.x * 16;
    __shared__ __align__(16) float ceL[16][128];
    __shared__ int sids[16], cids[16];
    if (tid < 16) sids[tid] = sent[t0 + tid];
    else if (tid < 32) cids[tid - 16] = csent[t0 + tid - 16];
    __syncthreads();
    {
        int f4 = tid;
        for (int q = 0; q < 2; ++q, f4 += 256) {
            int r = f4 >> 5, k4 = f4 & 31;
            float4 v = *(const float4*)&cemb[(size_t)cids[r] * CEDIM + k4 * 4];
            *(float4*)&ceL[r][k4 * 4] = v;
        }
    }
    {
        int f4 = tid;
        for (int q = 0; q < 8; ++q, f4 += 256) {
            int r = f4 >> 7, k4 = f4 & 127;
            float4 v = *(const float4*)&wemb[(size_t)sids[r] * EDIM + k4 * 4];
            *(float4*)&we_g[(size_t)(t0 + r) * EDIM + k4 * 4] = v;
        }
    }
    __syncthreads();
    for (int q = 0; q < 4; ++q) {
        int j = q * 256 + tid;
        int d = j >> 9, r = j & 511;
        const float* Wih = d ? cWih_b : cWih_f;
        const float* cb = d ? cb_b : cb_f;
        float b = cb[r];
        float acc[16];
#pragma unroll
        for (int tt = 0; tt < 16; ++tt) acc[tt] = b;
        for (int k4 = 0; k4 < 32; ++k4) {
            float4 wv = *(const float4*)&Wih[r * CEDIM + k4 * 4];
#pragma unroll
            for (int tt = 0; tt < 16; ++tt) {
                acc[tt] += wv.x * ceL[tt][k4 * 4 + 0] + wv.y * ceL[tt][k4 * 4 + 1]
                         + wv.z * ceL[tt][k4 * 4 + 2] + wv.w * ceL[tt][k4 * 4 + 3];
            }
        }
#pragma unroll
        for (int tt = 0; tt < 16; ++tt)
            cgx[((size_t)d * SQ + (t0 + tt)) * 512 + r] = acc[tt];
    }
}

// ---------------------------------------------------------------------------
// K2: blocks 0..63 (res<2): char BiLSTM, 8 WGs/dir, 16 units/WG, 16 weight
//     floats/thread in registers. blocks 64+: GEMM wgx = we_g.wWih[:,:512]^T
// ---------------------------------------------------------------------------
__global__ __launch_bounds__(512, 2) void k2_charlstm_gemm(
    const float* __restrict__ cWhh_f, const float* __restrict__ cWhh_b,
    const float* __restrict__ cgx, float* __restrict__ cho,
    const float* __restrict__ we_g,
    const float* __restrict__ wWih_f, const float* __restrict__ wb_f,
    const float* __restrict__ wWih_b, const float* __restrict__ wb_b,
    float* __restrict__ wgx, int* __restrict__ sync_)
{
    const int tid = threadIdx.x;
    __shared__ __align__(16) float At[32][68];
    __shared__ __align__(16) float Bt[32][128];
    __shared__ __align__(16) float hstC[128];
    __shared__ float partC[8][65];

    if (blockIdx.x < 64) {
        if ((blockIdx.x & 7) > 1) return;
        const int dir = blockIdx.x & 7;
        const int wid = blockIdx.x >> 3;      // 0..7
        const int k = tid >> 6;               // chunk = wave id (0..7)
        const int r = tid & 63;               // g*16+u
        const int g = r >> 4, u = r & 15;
        const float* Whh = dir ? cWhh_b : cWhh_f;
        const int G = g * CHH + wid * 16 + u;
        const float4* wp = (const float4*)&Whh[(size_t)G * CHH + k * 16];
        float4 w0 = wp[0], w1 = wp[1], w2 = wp[2], w3 = wp[3];
        PIN4(w0) PIN4(w1) PIN4(w2) PIN4(w3)

        int* cfl = sync_ + 4096 + dir * 256;  // 8 flags, stride 32 ints
        const float* gxc = cgx + (size_t)dir * SQ * 512;
        float cst = 0.f;
        for (int t = 0; t < SQ; ++t) {
            const int x = dir ? (SQ - 1 - t) : t;
            float gxi = 0.f, gxf = 0.f, gxg = 0.f, gxo = 0.f;
            if (tid < 16) {
                const size_t gb = (size_t)x * 512 + wid * 16 + tid;
                gxi = gxc[gb]; gxf = gxc[gb + 128];
                gxg = gxc[gb + 256]; gxo = gxc[gb + 384];
            }
            if (t == 0) {
                if (tid < 32) *(float4*)&hstC[tid * 4] = make_float4(0, 0, 0, 0);
            } else if (k == 0) {              // wave0: poll all 8 flags + stage h
                const int* fp = &cfl[(tid & 7) * 32];
                int v = ld_flag(fp);
                while (!__all(v >= t)) {
                    __builtin_amdgcn_s_sleep(1);
                    v = ld_flag(fp);
                }
                const int xp = dir ? (x + 1) : (x - 1);
                const float* hp = &cho[(size_t)xp * 256 + dir * CHH];
                ld_h2(hp + tid * 2, &hstC[tid * 2]);
            }
            __syncthreads();
            float a0 = 0.f, a1 = 0.f, a2 = 0.f, a3 = 0.f;
            const float* hc = &hstC[k * 16];
            FMA4(w0, 0) FMA4(w1, 4) FMA4(w2, 8) FMA4(w3, 12)
            partC[k][r] = (a0 + a1) + (a2 + a3);
            __syncthreads();
            if (tid < 16) {
                float s0 = 0.f, s1 = 0.f, s2 = 0.f, s3 = 0.f;
#pragma unroll
                for (int w8 = 0; w8 < 8; ++w8) {
                    s0 += partC[w8][tid];      s1 += partC[w8][16 + tid];
                    s2 += partC[w8][32 + tid]; s3 += partC[w8][48 + tid];
                }
                float iv = s0 + gxi, fv = s1 + gxf, gv = s2 + gxg, ov = s3 + gxo;
                cst = sigf(fv) * cst + sigf(iv) * tanhf(gv);
                float h = sigf(ov) * tanhf(cst);
                st_h(&cho[(size_t)x * 256 + dir * CHH + wid * 16 + tid], h);
                asm volatile("s_waitcnt vmcnt(0)" ::: "memory");
                if (tid == 0) st_flag(&cfl[wid * 32], t + 1);
            }
        }
        return;
    }
    // ---------------- GEMM (word-emb part of word gx) ----------------
    const int tile = blockIdx.x - 64;
    const int dir = tile >> 10;
    const int rem = tile & 1023;
    const int mb = rem >> 4;
    const int nb = rem & 15;
    const float* Wih = dir ? wWih_b : wWih_f;
    const float* wb = dir ? wb_b : wb_f;
    float* C = wgx + (size_t)dir * SQ * 2048;
    const int tm = tid >> 5, tn = tid & 31;
    float acc[4][4];
#pragma unroll
    for (int i = 0; i < 4; ++i)
#pragma unroll
        for (int jj = 0; jj < 4; ++jj) acc[i][jj] = 0.f;
    for (int kb = 0; kb < 16; ++kb) {
        {
            int rowm = tid >> 3, k4 = tid & 7;
            float4 v = *(const float4*)&we_g[(size_t)(mb * 64 + rowm) * EDIM + kb * 32 + k4 * 4];
            At[k4 * 4 + 0][rowm] = v.x; At[k4 * 4 + 1][rowm] = v.y;
            At[k4 * 4 + 2][rowm] = v.z; At[k4 * 4 + 3][rowm] = v.w;
        }
#pragma unroll
        for (int q = 0; q < 2; ++q) {
            int f4 = q * 512 + tid;
            int rr = f4 >> 3, k4 = f4 & 7;
            float4 v = *(const float4*)&Wih[(size_t)(nb * 128 + rr) * 768 + kb * 32 + k4 * 4];
            Bt[k4 * 4 + 0][rr] = v.x; Bt[k4 * 4 + 1][rr] = v.y;
            Bt[k4 * 4 + 2][rr] = v.z; Bt[k4 * 4 + 3][rr] = v.w;
        }
        __syncthreads();
#pragma unroll
        for (int kk = 0; kk < 32; ++kk) {
            float4 a4 = *(const float4*)&At[kk][tm * 4];
            float4 b4 = *(const float4*)&Bt[kk][tn * 4];
            acc[0][0] += a4.x * b4.x; acc[0][1] += a4.x * b4.y; acc[0][2] += a4.x * b4.z; acc[0][3] += a4.x * b4.w;
            acc[1][0] += a4.y * b4.x; acc[1][1] += a4.y * b4.y; acc[1][2] += a4.y * b4.z; acc[1][3] += a4.y * b4.w;
            acc[2][0] += a4.z * b4.x; acc[2][1] += a4.z * b4.y; acc[2][2] += a4.z * b4.z; acc[2][3] += a4.z * b4.w;
            acc[3][0] += a4.w * b4.x; acc[3][1] += a4.w * b4.y; acc[3][2] += a4.w * b4.z; acc[3][3] += a4.w * b4.w;
        }
        __syncthreads();
    }
    float4 wbv = *(const float4*)&wb[nb * 128 + tn * 4];
#pragma unroll
    for (int i = 0; i < 4; ++i) {
        float4 o;
        o.x = acc[i][0] + wbv.x; o.y = acc[i][1] + wbv.y;
        o.z = acc[i][2] + wbv.z; o.w = acc[i][3] + wbv.w;
        *(float4*)&C[(size_t)(mb * 64 + tm * 4 + i) * 2048 + nb * 128 + tn * 4] = o;
    }
}

// ---------------------------------------------------------------------------
// K3: wgx += char_out . wWih[:,512:768]^T
// ---------------------------------------------------------------------------
__global__ __launch_bounds__(512, 2) void k3_gemm_char(
    const float* __restrict__ cho,
    const float* __restrict__ wWih_f, const float* __restrict__ wWih_b,
    float* __restrict__ wgx)
{
    const int tid = threadIdx.x;
    const int tile = blockIdx.x;
    const int dir = tile >> 10;
    const int rem = tile & 1023;
    const int mb = rem >> 4, nb = rem & 15;
    const float* Wih = dir ? wWih_b : wWih_f;
    float* C = wgx + (size_t)dir * SQ * 2048;
    __shared__ __align__(16) float At[32][68];
    __shared__ __align__(16) float Bt[32][128];
    const int tm = tid >> 5, tn = tid & 31;
    float acc[4][4];
#pragma unroll
    for (int i = 0; i < 4; ++i)
#pragma unroll
        for (int jj = 0; jj < 4; ++jj) acc[i][jj] = 0.f;
    for (int kb = 0; kb < 8; ++kb) {
        {
            int rowm = tid >> 3, k4 = tid & 7;
            float4 v = *(const float4*)&cho[(size_t)(mb * 64 + rowm) * 256 + kb * 32 + k4 * 4];
            At[k4 * 4 + 0][rowm] = v.x; At[k4 * 4 + 1][rowm] = v.y;
            At[k4 * 4 + 2][rowm] = v.z; At[k4 * 4 + 3][rowm] = v.w;
        }
#pragma unroll
        for (int q = 0; q < 2; ++q) {
            int f4 = q * 512 + tid;
            int rr = f4 >> 3, k4 = f4 & 7;
            float4 v = *(const float4*)&Wih[(size_t)(nb * 128 + rr) * 768 + 512 + kb * 32 + k4 * 4];
            Bt[k4 * 4 + 0][rr] = v.x; Bt[k4 * 4 + 1][rr] = v.y;
            Bt[k4 * 4 + 2][rr] = v.z; Bt[k4 * 4 + 3][rr] = v.w;
        }
        __syncthreads();
#pragma unroll
        for (int kk = 0; kk < 32; ++kk) {
            float4 a4 = *(const float4*)&At[kk][tm * 4];
            float4 b4 = *(const float4*)&Bt[kk][tn * 4];
            acc[0][0] += a4.x * b4.x; acc[0][1] += a4.x * b4.y; acc[0][2] += a4.x * b4.z; acc[0][3] += a4.x * b4.w;
            acc[1][0] += a4.y * b4.x; acc[1][1] += a4.y * b4.y; acc[1][2] += a4.y * b4.z; acc[1][3] += a4.y * b4.w;
            acc[2][0] += a4.z * b4.x; acc[2][1] += a4.z * b4.y; acc[2][2] += a4.z * b4.z; acc[2][3] += a4.z * b4.w;
            acc[3][0] += a4.w * b4.x; acc[3][1] += a4.w * b4.y; acc[3][2] += a4.w * b4.z; acc[3][3] += a4.w * b4.w;
        }
        __syncthreads();
    }
#pragma unroll
    for (int i = 0; i < 4; ++i) {
        float* cp = &C[(size_t)(mb * 64 + tm * 4 + i) * 2048 + nb * 128 + tn * 4];
        float4 o = *(float4*)cp;
        o.x += acc[i][0]; o.y += acc[i][1]; o.z += acc[i][2]; o.w += acc[i][3];
        *(float4*)cp = o;
    }
}

// ---------------------------------------------------------------------------
// K4: word BiLSTM. 32 WGs/direction x 1024 threads (16 units/WG, 32 weight
//     floats/thread). Grid = 256 blocks @ 1 block/CU -> always co-resident.
//     Sync: per-WG monotonic flags + relaxed agent atomics (proven recipe).
// ---------------------------------------------------------------------------
__global__ __launch_bounds__(1024, 4) void k4_word_lstm(
    const float* __restrict__ wWhh_f, const float* __restrict__ wWhh_b,
    const float* __restrict__ wgx, float* __restrict__ lstm, int* __restrict__ sync_)
{
    const int res = blockIdx.x & 7;
    if (res > 1) return;
    const int dir = res;
    const int wid = blockIdx.x >> 3;      // 0..31
    const int tid = threadIdx.x;
    const int k = tid >> 6;               // h-chunk = wave id (0..15)
    const int r = tid & 63;               // g*16+u
    const int g = r >> 4, u = r & 15;
    const float* Whh = dir ? wWhh_b : wWhh_f;
    const int G = g * WH + wid * 16 + u;
    const float4* wp = (const float4*)&Whh[(size_t)G * WH + k * 32];
    float4 w0 = wp[0], w1 = wp[1], w2 = wp[2], w3 = wp[3];
    float4 w4 = wp[4], w5 = wp[5], w6 = wp[6], w7 = wp[7];
    PIN4(w0) PIN4(w1) PIN4(w2) PIN4(w3) PIN4(w4) PIN4(w5) PIN4(w6) PIN4(w7)

    __shared__ __align__(16) float hst[512];
    __shared__ float part[16][65];

    int* flags = sync_ + dir * 2048;      // 32 flags, stride 32 ints
    const float* gx = wgx + (size_t)dir * SQ * 2048;
    float cst = 0.f;
    for (int t = 0; t < SQ; ++t) {
        const int x = dir ? (SQ - 1 - t) : t;
        float gxi = 0.f, gxf = 0.f, gxg = 0.f, gxo = 0.f;
        if (tid < 16) {
            const size_t gb = (size_t)x * 2048 + wid * 16 + tid;
            gxi = gx[gb]; gxf = gx[gb + 512];
            gxg = gx[gb + 1024]; gxo = gx[gb + 1536];
        }
        if (t == 0) {
            if (tid < 128) *(float4*)&hst[tid * 4] = make_float4(0, 0, 0, 0);
        } else if (tid < 64) {            // wave0: poll all 32 flags + stage h
            const int* fp = &flags[(tid & 31) * 32];
            int v = ld_flag(fp);
            while (!__all(v >= t)) {
                __builtin_amdgcn_s_sleep(1);
                v = ld_flag(fp);
            }
            const int xp = dir ? (x + 1) : (x - 1);
            const float* hp = &lstm[(size_t)xp * 1024 + dir * WH];
            ld_h2(hp + tid * 8 + 0, &hst[tid * 8 + 0]);
            ld_h2(hp + tid * 8 + 2, &hst[tid * 8 + 2]);
            ld_h2(hp + tid * 8 + 4, &hst[tid * 8 + 4]);
            ld_h2(hp + tid * 8 + 6, &hst[tid * 8 + 6]);
        }
        __syncthreads();
        float a0 = 0.f, a1 = 0.f, a2 = 0.f, a3 = 0.f;
        const float* hc = &hst[k * 32];
        FMA4(w0, 0)  FMA4(w1, 4)  FMA4(w2, 8)  FMA4(w3, 12)
        FMA4(w4, 16) FMA4(w5, 20) FMA4(w6, 24) FMA4(w7, 28)
        part[k][r] = (a0 + a1) + (a2 + a3);
        __syncthreads();
        if (tid < 16) {
            float s0 = 0.f, s1 = 0.f, s2 = 0.f, s3 = 0.f;
#pragma unroll
            for (int kk = 0; kk < 16; ++kk) {
                s0 += part[kk][tid];      s1 += part[kk][16 + tid];
                s2 += part[kk][32 + tid]; s3 += part[kk][48 + tid];
            }
            float iv = s0 + gxi, fv = s1 + gxf, gv = s2 + gxg, ov = s3 + gxo;
            cst = sigf(fv) * cst + sigf(iv) * tanhf(gv);
            float h = sigf(ov) * tanhf(cst);
            st_h(&lstm[(size_t)x * 1024 + dir * WH + wid * 16 + tid], h);
            asm volatile("s_waitcnt vmcnt(0)" ::: "memory");
            if (tid == 0) st_flag(&flags[wid * 32], t + 1);
        }
    }
}

// ---------------------------------------------------------------------------
// K5: emissions = lstm_out @ W_tag^T + b_tag
// ---------------------------------------------------------------------------
__global__ __launch_bounds__(64) void k5_emis(
    const float* __restrict__ lstm, const float* __restrict__ Wtag,
    const float* __restrict__ btag, float* __restrict__ emis)
{
    const int t = blockIdx.x, tid = threadIdx.x;
    __shared__ __align__(16) float rowL[1024];
#pragma unroll
    for (int q = 0; q < 4; ++q) {
        int f4 = q * 64 + tid;
        *(float4*)&rowL[f4 * 4] = *(const float4*)&lstm[(size_t)t * 1024 + f4 * 4];
    }
    __syncthreads();
    if (tid < NT) {
        float a0 = 0.f, a1 = 0.f, a2 = 0.f, a3 = 0.f;
        const float* wr = Wtag + (size_t)tid * 1024;
        for (int k4 = 0; k4 < 256; ++k4) {
            float4 wv = *(const float4*)&wr[k4 * 4];
            a0 += wv.x * rowL[k4 * 4 + 0];
            a1 += wv.y * rowL[k4 * 4 + 1];
            a2 += wv.z * rowL[k4 * 4 + 2];
            a3 += wv.w * rowL[k4 * 4 + 3];
        }
        emis[(size_t)t * NT + tid] = btag[tid] + (a0 + a1) + (a2 + a3);
    }
}

// ---------------------------------------------------------------------------
// K6a: Viterbi forward (sequential)
// ---------------------------------------------------------------------------
__global__ __launch_bounds__(256) void k6a_viterbi(
    const float* __restrict__ emis, const float* __restrict__ start_t,
    const float* __restrict__ end_t, const float* __restrict__ trans,
    unsigned char* __restrict__ bpb, int* __restrict__ last)
{
    const int tid = threadIdx.x;
    const int g = tid >> 6, c = tid & 63;
    __shared__ float sc[64];
    __shared__ float pbest[4][64];
    __shared__ int pbp[4][64];
    const int p0 = g * 13;
    float tr[13];
#pragma unroll
    for (int i = 0; i < 13; ++i) {
        int p = p0 + i;
        tr[i] = (c < NT && p < NT) ? trans[p * NT + c] : -1e30f;
    }
    if (tid < 64) sc[tid] = (tid < NT) ? (start_t[tid] + emis[tid]) : -1e30f;
    __syncthreads();
    for (int t = 1; t < SQ; ++t) {
        float best = -1e30f; int bp = 0;
#pragma unroll
        for (int i = 0; i < 13; ++i) {
            float v = sc[p0 + i] + tr[i];
            if (v > best) { best = v; bp = p0 + i; }
        }
        pbest[g][c] = best; pbp[g][c] = bp;
        __syncthreads();
        if (tid < NT) {
            float b = pbest[0][tid]; int bb = pbp[0][tid];
#pragma unroll
            for (int gg = 1; gg < 4; ++gg) {
                float v = pbest[gg][tid];
                if (v > b) { b = v; bb = pbp[gg][tid]; }
            }
            bpb[(size_t)t * NT + tid] = (unsigned char)bb;
            sc[tid] = b + emis[(size_t)t * NT + tid];
        }
        __syncthreads();
    }
    if (tid == 0) {
        float b = -1e30f; int bi = 0;
        for (int cc = 0; cc < NT; ++cc) {
            float v = sc[cc] + end_t[cc];
            if (v > b) { b = v; bi = cc; }
        }
        *last = bi;
    }
}

// K6b: per-chunk end-tag -> end-of-previous-chunk-tag maps
__global__ __launch_bounds__(64) void k6b_maps(
    const unsigned char* __restrict__ bpb, int* __restrict__ map_)
{
    const int k = blockIdx.x;
    const int e = threadIdx.x;
    if (k == 0 || e >= NT) return;
    int tag = e;
    for (int i = 63; i >= 0; --i) {
        int t = k * 64 + i;
        tag = bpb[(size_t)t * NT + tag];
    }
    map_[k * NT + e] = tag;
}

// K6c: stitch chunk boundary tags, emit path
__global__ __launch_bounds__(64) void k6c_backtrack(
    const unsigned char* __restrict__ bpb, const int* __restrict__ map_,
    const int* __restrict__ last, int* __restrict__ path)
{
    __shared__ int B[64];
    if (threadIdx.x == 0) {
        int tag = *last;
        B[63] = tag;
        for (int k = 63; k >= 1; --k) {
            tag = map_[k * NT + tag];
            B[k - 1] = tag;
        }
    }
    __syncthreads();
    const int k = threadIdx.x;
    int tag = B[k];
    for (int i = 63; i >= 0; --i) {
        int t = k * 64 + i;
        path[t] = tag;
        if (t >= 1) tag = bpb[(size_t)t * NT + tag];
    }
}

// ---------------------------------------------------------------------------
extern "C" void kernel_launch(void* const* d_in, const int* in_sizes, int n_in,
                              void* d_out, int out_size, void* d_ws, size_t ws_size,
                              hipStream_t stream)
{
    const int* sent = (const int*)d_in[0];
    const int* csent = (const int*)d_in[1];
    const float* wemb = (const float*)d_in[2];
    const float* cemb = (const float*)d_in[3];
    const float* cWih_f = (const float*)d_in[4];
    const float* cWhh_f = (const float*)d_in[5];
    const float* cb_f = (const float*)d_in[6];
    const float* cWih_b = (const float*)d_in[7];
    const float* cWhh_b = (const float*)d_in[8];
    const float* cb_b = (const float*)d_in[9];
    const float* wWih_f = (const float*)d_in[10];
    const float* wWhh_f = (const float*)d_in[11];
    const float* wb_f = (const float*)d_in[12];
    const float* wWih_b = (const float*)d_in[13];
    const float* wWhh_b = (const float*)d_in[14];
    const float* wb_b = (const float*)d_in[15];
    const float* Wtag = (const float*)d_in[16];
    const float* btag = (const float*)d_in[17];
    const float* start_t = (const float*)d_in[18];
    const float* end_t = (const float*)d_in[19];
    const float* trans = (const float*)d_in[20];
    int* path = (int*)d_out;

    float* ws = (float*)d_ws;
    float* we_g = ws;                                   // SQ*EDIM
    float* cgx  = we_g + (size_t)SQ * EDIM;             // 2*SQ*512
    float* cho  = cgx + (size_t)2 * SQ * 512;           // SQ*256
    float* wgx  = cho + (size_t)SQ * 256;               // 2*SQ*2048
    float* lstm = wgx + (size_t)2 * SQ * 2048;          // SQ*1024
    float* emis = lstm + (size_t)SQ * 1024;             // SQ*NT
    int* sync_  = (int*)(emis + (size_t)SQ * NT);       // 8192 ints
    int* map_   = sync_ + 8192;                         // 64*NT
    int* lastp  = map_ + 64 * NT;                       // 1 (+pad)
    unsigned char* bpb = (unsigned char*)(lastp + 4);   // SQ*NT bytes

    (void)hipMemsetAsync(sync_, 0, 8192 * sizeof(int), stream);

    k1_gather_cgx<<<SQ / 16, 256, 0, stream>>>(sent, csent, wemb, cemb,
                                               cWih_f, cb_f, cWih_b, cb_b, we_g, cgx);
    k2_charlstm_gemm<<<64 + 2048, 512, 0, stream>>>(cWhh_f, cWhh_b, cgx, cho, we_g,
                                                    wWih_f, wb_f, wWih_b, wb_b, wgx, sync_);
    k3_gemm_char<<<2048, 512, 0, stream>>>(cho, wWih_f, wWih_b, wgx);
    k4_word_lstm<<<256, 1024, 0, stream>>>(wWhh_f, wWhh_b, wgx, lstm, sync_);
    k5_emis<<<SQ, 64, 0, stream>>>(lstm, Wtag, btag, emis);
    k6a_viterbi<<<1, 256, 0, stream>>>(emis, start_t, end_t, trans, bpb, lastp);
    k6b_maps<<<64, 64, 0, stream>>>(bpb, map_);
    k6c_backtrack<<<1, 64, 0, stream>>>(bpb, map_, lastp, path);
}

// Round 10
// 17071.336 us; speedup vs baseline: 1.0798x; 1.0758x over previous
//
#include <hip/hip_runtime.h>
#include <math.h>

#define SQ   4096
#define EDIM 512
#define CEDIM 128
#define CHH  128
#define WH   512
#define NT   50

typedef unsigned long long ull;

__device__ __forceinline__ float sigf(float x) { return 1.0f / (1.0f + expf(-x)); }

#define PIN4(V) asm volatile("" : "+v"(V.x), "+v"(V.y), "+v"(V.z), "+v"(V.w));

// ---- tagged-pair helpers ----------------------------------------------------
// fast path: batched sc0 loads (L2-served, bypass L1); plain store write-through
// mirror path: relaxed agent-scope atomics (proven coherent recipe)
__device__ __forceinline__ void ld8x_sc0(const ull* p, ull& q0, ull& q1, ull& q2,
                                         ull& q3, ull& q4, ull& q5, ull& q6, ull& q7) {
    asm volatile("global_load_dwordx2 %0, %8, off sc0\n\t"
                 "global_load_dwordx2 %1, %8, off offset:8 sc0\n\t"
                 "global_load_dwordx2 %2, %8, off offset:16 sc0\n\t"
                 "global_load_dwordx2 %3, %8, off offset:24 sc0\n\t"
                 "global_load_dwordx2 %4, %8, off offset:32 sc0\n\t"
                 "global_load_dwordx2 %5, %8, off offset:40 sc0\n\t"
                 "global_load_dwordx2 %6, %8, off offset:48 sc0\n\t"
                 "global_load_dwordx2 %7, %8, off offset:56 sc0\n\t"
                 "s_waitcnt vmcnt(0)"
                 : "=&v"(q0), "=&v"(q1), "=&v"(q2), "=&v"(q3),
                   "=&v"(q4), "=&v"(q5), "=&v"(q6), "=&v"(q7)
                 : "v"(p) : "memory");
}
__device__ __forceinline__ void ld2x_sc0(const ull* p, ull& q0, ull& q1) {
    asm volatile("global_load_dwordx2 %0, %2, off sc0\n\t"
                 "global_load_dwordx2 %1, %2, off offset:8 sc0\n\t"
                 "s_waitcnt vmcnt(0)"
                 : "=&v"(q0), "=&v"(q1) : "v"(p) : "memory");
}
__device__ __forceinline__ ull ld_mir(const ull* p) {
    return __hip_atomic_load(p, __ATOMIC_RELAXED, __HIP_MEMORY_SCOPE_AGENT);
}
__device__ __forceinline__ void st_plain8(ull* p, ull v) {
    asm volatile("global_store_dwordx2 %0, %1, off" :: "v"(p), "v"(v) : "memory");
}
__device__ __forceinline__ void st_mir(ull* p, ull v) {
    __hip_atomic_store(p, v, __ATOMIC_RELAXED, __HIP_MEMORY_SCOPE_AGENT);
}
__device__ __forceinline__ unsigned umin2(unsigned a, unsigned b) { return a < b ? a : b; }

#define FMA4(W, off) { float4 h4 = *(const float4*)&hc[off]; \
    a0 += W.x * h4.x; a1 += W.y * h4.y; a2 += W.z * h4.z; a3 += W.w * h4.w; }

// ---------------------------------------------------------------------------
// K1: gather word/char embedding rows; compute char-LSTM input GEMM
// ---------------------------------------------------------------------------
__global__ __launch_bounds__(256) void k1_gather_cgx(
    const int* __restrict__ sent, const int* __restrict__ csent,
    const float* __restrict__ wemb, const float* __restrict__ cemb,
    const float* __restrict__ cWih_f, const float* __restrict__ cb_f,
    const float* __restrict__ cWih_b, const float* __restrict__ cb_b,
    float* __restrict__ we_g, float* __restrict__ cgx)
{
    const int tid = threadIdx.x;
    const int t0 = blockIdx.x * 16;
    __shared__ __align__(16) float ceL[16][128];
    __shared__ int sids[16], cids[16];
    if (tid < 16) sids[tid] = sent[t0 + tid];
    else if (tid < 32) cids[tid - 16] = csent[t0 + tid - 16];
    __syncthreads();
    {
        int f4 = tid;
        for (int q = 0; q < 2; ++q, f4 += 256) {
            int r = f4 >> 5, k4 = f4 & 31;
            float4 v = *(const float4*)&cemb[(size_t)cids[r] * CEDIM + k4 * 4];
            *(float4*)&ceL[r][k4 * 4] = v;
        }
    }
    {
        int f4 = tid;
        for (int q = 0; q < 8; ++q, f4 += 256) {
            int r = f4 >> 7, k4 = f4 & 127;
            float4 v = *(const float4*)&wemb[(size_t)sids[r] * EDIM + k4 * 4];
            *(float4*)&we_g[(size_t)(t0 + r) * EDIM + k4 * 4] = v;
        }
    }
    __syncthreads();
    for (int q = 0; q < 4; ++q) {
        int j = q * 256 + tid;
        int d = j >> 9, r = j & 511;
        const float* Wih = d ? cWih_b : cWih_f;
        const float* cb = d ? cb_b : cb_f;
        float b = cb[r];
        float acc[16];
#pragma unroll
        for (int tt = 0; tt < 16; ++tt) acc[tt] = b;
        for (int k4 = 0; k4 < 32; ++k4) {
            float4 wv = *(const float4*)&Wih[r * CEDIM + k4 * 4];
#pragma unroll
            for (int tt = 0; tt < 16; ++tt) {
                acc[tt] += wv.x * ceL[tt][k4 * 4 + 0] + wv.y * ceL[tt][k4 * 4 + 1]
                         + wv.z * ceL[tt][k4 * 4 + 2] + wv.w * ceL[tt][k4 * 4 + 3];
            }
        }
#pragma unroll
        for (int tt = 0; tt < 16; ++tt)
            cgx[((size_t)d * SQ + (t0 + tt)) * 512 + r] = acc[tt];
    }
}

// ---------------------------------------------------------------------------
// K2: blocks 0..63 (res<2): char BiLSTM, 8 WGs/dir, 16 units/WG, tagged-pair
//     h exchange. blocks 64+: GEMM wgx = we_g.wWih[:,:512]^T + wb
// ---------------------------------------------------------------------------
__global__ __launch_bounds__(512, 2) void k2_charlstm_gemm(
    const float* __restrict__ cWhh_f, const float* __restrict__ cWhh_b,
    const float* __restrict__ cgx, float* __restrict__ cho,
    const float* __restrict__ we_g,
    const float* __restrict__ wWih_f, const float* __restrict__ wb_f,
    const float* __restrict__ wWih_b, const float* __restrict__ wb_b,
    float* __restrict__ wgx, ull* __restrict__ pairs)
{
    const int tid = threadIdx.x;
    __shared__ __align__(16) float At[32][68];
    __shared__ __align__(16) float Bt[32][128];
    __shared__ __align__(16) float hstC[128];
    __shared__ float partC[8][65];

    if (blockIdx.x < 64) {
        if ((blockIdx.x & 7) > 1) return;
        const int dir = blockIdx.x & 7;
        const int wid = blockIdx.x >> 3;      // 0..7
        const int k = tid >> 6;               // chunk = wave id (0..7)
        const int r = tid & 63;               // g*16+u
        const int g = r >> 4, u = r & 15;
        const float* Whh = dir ? cWhh_b : cWhh_f;
        const int G = g * CHH + wid * 16 + u;
        const float4* wp = (const float4*)&Whh[(size_t)G * CHH + k * 16];
        float4 w0 = wp[0], w1 = wp[1], w2 = wp[2], w3 = wp[3];
        PIN4(w0) PIN4(w1) PIN4(w2) PIN4(w3)

        ull* cpf = pairs + 4096;   // [2][2][128]
        ull* cpm = pairs + 4608;
        const float* gxc = cgx + (size_t)dir * SQ * 512;
        float cst = 0.f;
        int useFast = 1, alive = 1;
        for (int t = 0; t < SQ; ++t) {
            const int x = dir ? (SQ - 1 - t) : t;
            float gxi = 0.f, gxf = 0.f, gxg = 0.f, gxo = 0.f;
            if (tid < 16) {
                const size_t gb = (size_t)x * 512 + wid * 16 + tid;
                gxi = gxc[gb]; gxf = gxc[gb + 128];
                gxg = gxc[gb + 256]; gxo = gxc[gb + 384];
            }
            if (t == 0) {
                if (tid < 32) *(float4*)&hstC[tid * 4] = make_float4(0, 0, 0, 0);
            } else if (k == 0) {              // wave0: poll pairs + stage h
                const size_t boff = ((size_t)((t - 1) & 1) * 2 + dir) * 128 + tid * 2;
                const ull* pf = cpf + boff;
                const ull* pm = cpm + boff;
                ull q0 = 0, q1 = 0;
                int spins = 0;
                while (alive) {
                    if (useFast) ld2x_sc0(pf, q0, q1);
                    else { q0 = ld_mir(pm + 0); q1 = ld_mir(pm + 1); }
                    unsigned tm = umin2((unsigned)(q0 >> 32), (unsigned)(q1 >> 32));
                    if (__all(tm >= (unsigned)t)) break;
                    ++spins;
                    if (useFast && spins > 2048) { useFast = 0; spins = 0; }
                    if (!useFast && spins > (1 << 20)) alive = 0;
                    __builtin_amdgcn_s_sleep(1);
                }
                hstC[tid * 2 + 0] = __uint_as_float((unsigned)q0);
                hstC[tid * 2 + 1] = __uint_as_float((unsigned)q1);
            }
            __syncthreads();
            float a0 = 0.f, a1 = 0.f, a2 = 0.f, a3 = 0.f;
            const float* hc = &hstC[k * 16];
            FMA4(w0, 0) FMA4(w1, 4) FMA4(w2, 8) FMA4(w3, 12)
            partC[k][r] = (a0 + a1) + (a2 + a3);
            __syncthreads();
            if (tid < 16) {
                float s0 = 0.f, s1 = 0.f, s2 = 0.f, s3 = 0.f;
#pragma unroll
                for (int w8 = 0; w8 < 8; ++w8) {
                    s0 += partC[w8][tid];      s1 += partC[w8][16 + tid];
                    s2 += partC[w8][32 + tid]; s3 += partC[w8][48 + tid];
                }
                float iv = s0 + gxi, fv = s1 + gxf, gv = s2 + gxg, ov = s3 + gxo;
                cst = sigf(fv) * cst + sigf(iv) * tanhf(gv);
                float h = sigf(ov) * tanhf(cst);
                const int unit = wid * 16 + tid;
                cho[(size_t)x * 256 + dir * CHH + unit] = h;   // plain, read by K3 after kernel end
                ull q = ((ull)(unsigned)(t + 1) << 32) | (ull)__float_as_uint(h);
                const size_t poff = ((size_t)(t & 1) * 2 + dir) * 128 + unit;
                st_plain8(cpf + poff, q);
                st_mir(cpm + poff, q);
            }
        }
        return;
    }
    // ---------------- GEMM (word-emb part of word gx) ----------------
    const int tile = blockIdx.x - 64;
    const int dir = tile >> 10;
    const int rem = tile & 1023;
    const int mb = rem >> 4;
    const int nb = rem & 15;
    const float* Wih = dir ? wWih_b : wWih_f;
    const float* wb = dir ? wb_b : wb_f;
    float* C = wgx + (size_t)dir * SQ * 2048;
    const int tm = tid >> 5, tn = tid & 31;
    float acc[4][4];
#pragma unroll
    for (int i = 0; i < 4; ++i)
#pragma unroll
        for (int jj = 0; jj < 4; ++jj) acc[i][jj] = 0.f;
    for (int kb = 0; kb < 16; ++kb) {
        {
            int rowm = tid >> 3, k4 = tid & 7;
            float4 v = *(const float4*)&we_g[(size_t)(mb * 64 + rowm) * EDIM + kb * 32 + k4 * 4];
            At[k4 * 4 + 0][rowm] = v.x; At[k4 * 4 + 1][rowm] = v.y;
            At[k4 * 4 + 2][rowm] = v.z; At[k4 * 4 + 3][rowm] = v.w;
        }
#pragma unroll
        for (int q = 0; q < 2; ++q) {
            int f4 = q * 512 + tid;
            int rr = f4 >> 3, k4 = f4 & 7;
            float4 v = *(const float4*)&Wih[(size_t)(nb * 128 + rr) * 768 + kb * 32 + k4 * 4];
            Bt[k4 * 4 + 0][rr] = v.x; Bt[k4 * 4 + 1][rr] = v.y;
            Bt[k4 * 4 + 2][rr] = v.z; Bt[k4 * 4 + 3][rr] = v.w;
        }
        __syncthreads();
#pragma unroll
        for (int kk = 0; kk < 32; ++kk) {
            float4 a4 = *(const float4*)&At[kk][tm * 4];
            float4 b4 = *(const float4*)&Bt[kk][tn * 4];
            acc[0][0] += a4.x * b4.x; acc[0][1] += a4.x * b4.y; acc[0][2] += a4.x * b4.z; acc[0][3] += a4.x * b4.w;
            acc[1][0] += a4.y * b4.x; acc[1][1] += a4.y * b4.y; acc[1][2] += a4.y * b4.z; acc[1][3] += a4.y * b4.w;
            acc[2][0] += a4.z * b4.x; acc[2][1] += a4.z * b4.y; acc[2][2] += a4.z * b4.z; acc[2][3] += a4.z * b4.w;
            acc[3][0] += a4.w * b4.x; acc[3][1] += a4.w * b4.y; acc[3][2] += a4.w * b4.z; acc[3][3] += a4.w * b4.w;
        }
        __syncthreads();
    }
    float4 wbv = *(const float4*)&wb[nb * 128 + tn * 4];
#pragma unroll
    for (int i = 0; i < 4; ++i) {
        float4 o;
        o.x = acc[i][0] + wbv.x; o.y = acc[i][1] + wbv.y;
        o.z = acc[i][2] + wbv.z; o.w = acc[i][3] + wbv.w;
        *(float4*)&C[(size_t)(mb * 64 + tm * 4 + i) * 2048 + nb * 128 + tn * 4] = o;
    }
}

// ---------------------------------------------------------------------------
// K3: wgx += char_out . wWih[:,512:768]^T
// ---------------------------------------------------------------------------
__global__ __launch_bounds__(512, 2) void k3_gemm_char(
    const float* __restrict__ cho,
    const float* __restrict__ wWih_f, const float* __restrict__ wWih_b,
    float* __restrict__ wgx)
{
    const int tid = threadIdx.x;
    const int tile = blockIdx.x;
    const int dir = tile >> 10;
    const int rem = tile & 1023;
    const int mb = rem >> 4, nb = rem & 15;
    const float* Wih = dir ? wWih_b : wWih_f;
    float* C = wgx + (size_t)dir * SQ * 2048;
    __shared__ __align__(16) float At[32][68];
    __shared__ __align__(16) float Bt[32][128];
    const int tm = tid >> 5, tn = tid & 31;
    float acc[4][4];
#pragma unroll
    for (int i = 0; i < 4; ++i)
#pragma unroll
        for (int jj = 0; jj < 4; ++jj) acc[i][jj] = 0.f;
    for (int kb = 0; kb < 8; ++kb) {
        {
            int rowm = tid >> 3, k4 = tid & 7;
            float4 v = *(const float4*)&cho[(size_t)(mb * 64 + rowm) * 256 + kb * 32 + k4 * 4];
            At[k4 * 4 + 0][rowm] = v.x; At[k4 * 4 + 1][rowm] = v.y;
            At[k4 * 4 + 2][rowm] = v.z; At[k4 * 4 + 3][rowm] = v.w;
        }
#pragma unroll
        for (int q = 0; q < 2; ++q) {
            int f4 = q * 512 + tid;
            int rr = f4 >> 3, k4 = f4 & 7;
            float4 v = *(const float4*)&Wih[(size_t)(nb * 128 + rr) * 768 + 512 + kb * 32 + k4 * 4];
            Bt[k4 * 4 + 0][rr] = v.x; Bt[k4 * 4 + 1][rr] = v.y;
            Bt[k4 * 4 + 2][rr] = v.z; Bt[k4 * 4 + 3][rr] = v.w;
        }
        __syncthreads();
#pragma unroll
        for (int kk = 0; kk < 32; ++kk) {
            float4 a4 = *(const float4*)&At[kk][tm * 4];
            float4 b4 = *(const float4*)&Bt[kk][tn * 4];
            acc[0][0] += a4.x * b4.x; acc[0][1] += a4.x * b4.y; acc[0][2] += a4.x * b4.z; acc[0][3] += a4.x * b4.w;
            acc[1][0] += a4.y * b4.x; acc[1][1] += a4.y * b4.y; acc[1][2] += a4.y * b4.z; acc[1][3] += a4.y * b4.w;
            acc[2][0] += a4.z * b4.x; acc[2][1] += a4.z * b4.y; acc[2][2] += a4.z * b4.z; acc[2][3] += a4.z * b4.w;
            acc[3][0] += a4.w * b4.x; acc[3][1] += a4.w * b4.y; acc[3][2] += a4.w * b4.z; acc[3][3] += a4.w * b4.w;
        }
        __syncthreads();
    }
#pragma unroll
    for (int i = 0; i < 4; ++i) {
        float* cp = &C[(size_t)(mb * 64 + tm * 4 + i) * 2048 + nb * 128 + tn * 4];
        float4 o = *(float4*)cp;
        o.x += acc[i][0]; o.y += acc[i][1]; o.z += acc[i][2]; o.w += acc[i][3];
        *(float4*)cp = o;
    }
}

// ---------------------------------------------------------------------------
// K4: word BiLSTM. 32 WGs/direction x 1024 threads, tagged-pair h exchange:
//     one 8-byte (h, step-tag) word per unit, double-buffered by parity.
//     Fast path: plain store + sc0 poll (same-XCD L2). Mirror: agent atomics.
//     Sticky timeout fallback makes livelock impossible.
// ---------------------------------------------------------------------------
__global__ __launch_bounds__(1024, 4) void k4_word_lstm(
    const float* __restrict__ wWhh_f, const float* __restrict__ wWhh_b,
    const float* __restrict__ wgx, float* __restrict__ lstm, ull* __restrict__ pairs)
{
    const int res = blockIdx.x & 7;
    if (res > 1) return;
    const int dir = res;
    const int wid = blockIdx.x >> 3;      // 0..31
    const int tid = threadIdx.x;
    const int k = tid >> 6;               // h-chunk = wave id (0..15)
    const int r = tid & 63;               // g*16+u
    const int g = r >> 4, u = r & 15;
    const float* Whh = dir ? wWhh_b : wWhh_f;
    const int G = g * WH + wid * 16 + u;
    const float4* wp = (const float4*)&Whh[(size_t)G * WH + k * 32];
    float4 w0 = wp[0], w1 = wp[1], w2 = wp[2], w3 = wp[3];
    float4 w4 = wp[4], w5 = wp[5], w6 = wp[6], w7 = wp[7];
    PIN4(w0) PIN4(w1) PIN4(w2) PIN4(w3) PIN4(w4) PIN4(w5) PIN4(w6) PIN4(w7)

    __shared__ __align__(16) float hst[512];
    __shared__ float part[16][65];

    ull* wpf = pairs;            // [2][2][512] fast
    ull* wpm = pairs + 2048;     // mirror
    const float* gx = wgx + (size_t)dir * SQ * 2048;
    float cst = 0.f;
    int useFast = 1, alive = 1;
    for (int t = 0; t < SQ; ++t) {
        const int x = dir ? (SQ - 1 - t) : t;
        float gxi = 0.f, gxf = 0.f, gxg = 0.f, gxo = 0.f;
        if (tid < 16) {
            const size_t gb = (size_t)x * 2048 + wid * 16 + tid;
            gxi = gx[gb]; gxf = gx[gb + 512];
            gxg = gx[gb + 1024]; gxo = gx[gb + 1536];
        }
        if (t == 0) {
            if (tid < 128) *(float4*)&hst[tid * 4] = make_float4(0, 0, 0, 0);
        } else if (tid < 64) {            // wave0: poll 8 pairs/lane + stage h
            const size_t boff = ((size_t)((t - 1) & 1) * 2 + dir) * 512 + tid * 8;
            const ull* pf = wpf + boff;
            const ull* pm = wpm + boff;
            ull q0 = 0, q1 = 0, q2 = 0, q3 = 0, q4 = 0, q5 = 0, q6 = 0, q7 = 0;
            int spins = 0;
            while (alive) {
                if (useFast) {
                    ld8x_sc0(pf, q0, q1, q2, q3, q4, q5, q6, q7);
                } else {
                    q0 = ld_mir(pm + 0); q1 = ld_mir(pm + 1);
                    q2 = ld_mir(pm + 2); q3 = ld_mir(pm + 3);
                    q4 = ld_mir(pm + 4); q5 = ld_mir(pm + 5);
                    q6 = ld_mir(pm + 6); q7 = ld_mir(pm + 7);
                }
                unsigned tm = umin2(umin2(umin2((unsigned)(q0 >> 32), (unsigned)(q1 >> 32)),
                                          umin2((unsigned)(q2 >> 32), (unsigned)(q3 >> 32))),
                                    umin2(umin2((unsigned)(q4 >> 32), (unsigned)(q5 >> 32)),
                                          umin2((unsigned)(q6 >> 32), (unsigned)(q7 >> 32))));
                if (__all(tm >= (unsigned)t)) break;
                ++spins;
                if (useFast && spins > 2048) { useFast = 0; spins = 0; }
                if (!useFast && spins > (1 << 20)) alive = 0;
                __builtin_amdgcn_s_sleep(1);
            }
            float* hd = &hst[tid * 8];
            hd[0] = __uint_as_float((unsigned)q0); hd[1] = __uint_as_float((unsigned)q1);
            hd[2] = __uint_as_float((unsigned)q2); hd[3] = __uint_as_float((unsigned)q3);
            hd[4] = __uint_as_float((unsigned)q4); hd[5] = __uint_as_float((unsigned)q5);
            hd[6] = __uint_as_float((unsigned)q6); hd[7] = __uint_as_float((unsigned)q7);
        }
        __syncthreads();
        float a0 = 0.f, a1 = 0.f, a2 = 0.f, a3 = 0.f;
        const float* hc = &hst[k * 32];
        FMA4(w0, 0)  FMA4(w1, 4)  FMA4(w2, 8)  FMA4(w3, 12)
        FMA4(w4, 16) FMA4(w5, 20) FMA4(w6, 24) FMA4(w7, 28)
        part[k][r] = (a0 + a1) + (a2 + a3);
        __syncthreads();
        if (tid < 16) {
            float s0 = 0.f, s1 = 0.f, s2 = 0.f, s3 = 0.f;
#pragma unroll
            for (int kk = 0; kk < 16; ++kk) {
                s0 += part[kk][tid];      s1 += part[kk][16 + tid];
                s2 += part[kk][32 + tid]; s3 += part[kk][48 + tid];
            }
            float iv = s0 + gxi, fv = s1 + gxf, gv = s2 + gxg, ov = s3 + gxo;
            cst = sigf(fv) * cst + sigf(iv) * tanhf(gv);
            float h = sigf(ov) * tanhf(cst);
            const int unit = wid * 16 + tid;
            lstm[(size_t)x * 1024 + dir * WH + unit] = h;   // plain, read by K5 after kernel end
            ull q = ((ull)(unsigned)(t + 1) << 32) | (ull)__float_as_uint(h);
            const size_t poff = ((size_t)(t & 1) * 2 + dir) * 512 + unit;
            st_plain8(wpf + poff, q);
            st_mir(wpm + poff, q);
        }
    }
}

// ---------------------------------------------------------------------------
// K5: emissions = lstm_out @ W_tag^T + b_tag
// ---------------------------------------------------------------------------
__global__ __launch_bounds__(64) void k5_emis(
    const float* __restrict__ lstm, const float* __restrict__ Wtag,
    const float* __restrict__ btag, float* __restrict__ emis)
{
    const int t = blockIdx.x, tid = threadIdx.x;
    __shared__ __align__(16) float rowL[1024];
#pragma unroll
    for (int q = 0; q < 4; ++q) {
        int f4 = q * 64 + tid;
        *(float4*)&rowL[f4 * 4] = *(const float4*)&lstm[(size_t)t * 1024 + f4 * 4];
    }
    __syncthreads();
    if (tid < NT) {
        float a0 = 0.f, a1 = 0.f, a2 = 0.f, a3 = 0.f;
        const float* wr = Wtag + (size_t)tid * 1024;
        for (int k4 = 0; k4 < 256; ++k4) {
            float4 wv = *(const float4*)&wr[k4 * 4];
            a0 += wv.x * rowL[k4 * 4 + 0];
            a1 += wv.y * rowL[k4 * 4 + 1];
            a2 += wv.z * rowL[k4 * 4 + 2];
            a3 += wv.w * rowL[k4 * 4 + 3];
        }
        emis[(size_t)t * NT + tid] = btag[tid] + (a0 + a1) + (a2 + a3);
    }
}

// ---------------------------------------------------------------------------
// K6a: Viterbi forward (sequential)
// ---------------------------------------------------------------------------
__global__ __launch_bounds__(256) void k6a_viterbi(
    const float* __restrict__ emis, const float* __restrict__ start_t,
    const float* __restrict__ end_t, const float* __restrict__ trans,
    unsigned char* __restrict__ bpb, int* __restrict__ last)
{
    const int tid = threadIdx.x;
    const int g = tid >> 6, c = tid & 63;
    __shared__ float sc[64];
    __shared__ float pbest[4][64];
    __shared__ int pbp[4][64];
    const int p0 = g * 13;
    float tr[13];
#pragma unroll
    for (int i = 0; i < 13; ++i) {
        int p = p0 + i;
        tr[i] = (c < NT && p < NT) ? trans[p * NT + c] : -1e30f;
    }
    if (tid < 64) sc[tid] = (tid < NT) ? (start_t[tid] + emis[tid]) : -1e30f;
    __syncthreads();
    for (int t = 1; t < SQ; ++t) {
        float best = -1e30f; int bp = 0;
#pragma unroll
        for (int i = 0; i < 13; ++i) {
            float v = sc[p0 + i] + tr[i];
            if (v > best) { best = v; bp = p0 + i; }
        }
        pbest[g][c] = best; pbp[g][c] = bp;
        __syncthreads();
        if (tid < NT) {
            float b = pbest[0][tid]; int bb = pbp[0][tid];
#pragma unroll
            for (int gg = 1; gg < 4; ++gg) {
                float v = pbest[gg][tid];
                if (v > b) { b = v; bb = pbp[gg][tid]; }
            }
            bpb[(size_t)t * NT + tid] = (unsigned char)bb;
            sc[tid] = b + emis[(size_t)t * NT + tid];
        }
        __syncthreads();
    }
    if (tid == 0) {
        float b = -1e30f; int bi = 0;
        for (int cc = 0; cc < NT; ++cc) {
            float v = sc[cc] + end_t[cc];
            if (v > b) { b = v; bi = cc; }
        }
        *last = bi;
    }
}

// K6b: per-chunk end-tag -> end-of-previous-chunk-tag maps
__global__ __launch_bounds__(64) void k6b_maps(
    const unsigned char* __restrict__ bpb, int* __restrict__ map_)
{
    const int k = blockIdx.x;
    const int e = threadIdx.x;
    if (k == 0 || e >= NT) return;
    int tag = e;
    for (int i = 63; i >= 0; --i) {
        int t = k * 64 + i;
        tag = bpb[(size_t)t * NT + tag];
    }
    map_[k * NT + e] = tag;
}

// K6c: stitch chunk boundary tags, emit path
__global__ __launch_bounds__(64) void k6c_backtrack(
    const unsigned char* __restrict__ bpb, const int* __restrict__ map_,
    const int* __restrict__ last, int* __restrict__ path)
{
    __shared__ int B[64];
    if (threadIdx.x == 0) {
        int tag = *last;
        B[63] = tag;
        for (int k = 63; k >= 1; --k) {
            tag = map_[k * NT + tag];
            B[k - 1] = tag;
        }
    }
    __syncthreads();
    const int k = threadIdx.x;
    int tag = B[k];
    for (int i = 63; i >= 0; --i) {
        int t = k * 64 + i;
        path[t] = tag;
        if (t >= 1) tag = bpb[(size_t)t * NT + tag];
    }
}

// ---------------------------------------------------------------------------
extern "C" void kernel_launch(void* const* d_in, const int* in_sizes, int n_in,
                              void* d_out, int out_size, void* d_ws, size_t ws_size,
                              hipStream_t stream)
{
    const int* sent = (const int*)d_in[0];
    const int* csent = (const int*)d_in[1];
    const float* wemb = (const float*)d_in[2];
    const float* cemb = (const float*)d_in[3];
    const float* cWih_f = (const float*)d_in[4];
    const float* cWhh_f = (const float*)d_in[5];
    const float* cb_f = (const float*)d_in[6];
    const float* cWih_b = (const float*)d_in[7];
    const float* cWhh_b = (const float*)d_in[8];
    const float* cb_b = (const float*)d_in[9];
    const float* wWih_f = (const float*)d_in[10];
    const float* wWhh_f = (const float*)d_in[11];
    const float* wb_f = (const float*)d_in[12];
    const float* wWih_b = (const float*)d_in[13];
    const float* wWhh_b = (const float*)d_in[14];
    const float* wb_b = (const float*)d_in[15];
    const float* Wtag = (const float*)d_in[16];
    const float* btag = (const float*)d_in[17];
    const float* start_t = (const float*)d_in[18];
    const float* end_t = (const float*)d_in[19];
    const float* trans = (const float*)d_in[20];
    int* path = (int*)d_out;

    float* ws = (float*)d_ws;
    float* we_g = ws;                                   // SQ*EDIM
    float* cgx  = we_g + (size_t)SQ * EDIM;             // 2*SQ*512
    float* cho  = cgx + (size_t)2 * SQ * 512;           // SQ*256
    float* wgx  = cho + (size_t)SQ * 256;               // 2*SQ*2048
    float* lstm = wgx + (size_t)2 * SQ * 2048;          // SQ*1024
    float* emis = lstm + (size_t)SQ * 1024;             // SQ*NT
    ull* pairs  = (ull*)(emis + (size_t)SQ * NT);       // 5120 ulongs (40KB)
    int* map_   = (int*)(pairs + 5120);                 // 64*NT
    int* lastp  = map_ + 64 * NT;                       // 1 (+pad)
    unsigned char* bpb = (unsigned char*)(lastp + 4);   // SQ*NT bytes

    (void)hipMemsetAsync(pairs, 0, 5120 * sizeof(ull), stream);

    k1_gather_cgx<<<SQ / 16, 256, 0, stream>>>(sent, csent, wemb, cemb,
                                               cWih_f, cb_f, cWih_b, cb_b, we_g, cgx);
    k2_charlstm_gemm<<<64 + 2048, 512, 0, stream>>>(cWhh_f, cWhh_b, cgx, cho, we_g,
                                                    wWih_f, wb_f, wWih_b, wb_b, wgx, pairs);
    k3_gemm_char<<<2048, 512, 0, stream>>>(cho, wWih_f, wWih_b, wgx);
    k4_word_lstm<<<256, 1024, 0, stream>>>(wWhh_f, wWhh_b, wgx, lstm, pairs);
    k5_emis<<<SQ, 64, 0, stream>>>(lstm, Wtag, btag, emis);
    k6a_viterbi<<<1, 256, 0, stream>>>(emis, start_t, end_t, trans, bpb, lastp);
    k6b_maps<<<64, 64, 0, stream>>>(bpb, map_);
    k6c_backtrack<<<1, 64, 0, stream>>>(bpb, map_, lastp, path);
}

// Round 11
// 14136.449 us; speedup vs baseline: 1.3040x; 1.2076x over previous
//
#include <hip/hip_runtime.h>
#include <math.h>

#define SQ   4096
#define EDIM 512
#define CEDIM 128
#define CHH  128
#define WH   512
#define NT   50

typedef unsigned long long ull;

__device__ __forceinline__ float sigf(float x) { return 1.0f / (1.0f + expf(-x)); }

#define PIN4(V) asm volatile("" : "+v"(V.x), "+v"(V.y), "+v"(V.z), "+v"(V.w));

// ---- tagged-pair helpers (unchanged from round 10; proven) -------------------
__device__ __forceinline__ void ld8x_sc0(const ull* p, ull& q0, ull& q1, ull& q2,
                                         ull& q3, ull& q4, ull& q5, ull& q6, ull& q7) {
    asm volatile("global_load_dwordx2 %0, %8, off sc0\n\t"
                 "global_load_dwordx2 %1, %8, off offset:8 sc0\n\t"
                 "global_load_dwordx2 %2, %8, off offset:16 sc0\n\t"
                 "global_load_dwordx2 %3, %8, off offset:24 sc0\n\t"
                 "global_load_dwordx2 %4, %8, off offset:32 sc0\n\t"
                 "global_load_dwordx2 %5, %8, off offset:40 sc0\n\t"
                 "global_load_dwordx2 %6, %8, off offset:48 sc0\n\t"
                 "global_load_dwordx2 %7, %8, off offset:56 sc0\n\t"
                 "s_waitcnt vmcnt(0)"
                 : "=&v"(q0), "=&v"(q1), "=&v"(q2), "=&v"(q3),
                   "=&v"(q4), "=&v"(q5), "=&v"(q6), "=&v"(q7)
                 : "v"(p) : "memory");
}
__device__ __forceinline__ ull ld_mir(const ull* p) {
    return __hip_atomic_load(p, __ATOMIC_RELAXED, __HIP_MEMORY_SCOPE_AGENT);
}
__device__ __forceinline__ void st_plain8(ull* p, ull v) {
    asm volatile("global_store_dwordx2 %0, %1, off" :: "v"(p), "v"(v) : "memory");
}
__device__ __forceinline__ void st_mir(ull* p, ull v) {
    __hip_atomic_store(p, v, __ATOMIC_RELAXED, __HIP_MEMORY_SCOPE_AGENT);
}
__device__ __forceinline__ unsigned umin2(unsigned a, unsigned b) { return a < b ? a : b; }

#define FMA4(W, off) { float4 h4 = *(const float4*)&hc[off]; \
    a0 += W.x * h4.x; a1 += W.y * h4.y; a2 += W.z * h4.z; a3 += W.w * h4.w; }

// ---------------------------------------------------------------------------
// K1: gather word/char embedding rows; compute char-LSTM input GEMM
// ---------------------------------------------------------------------------
__global__ __launch_bounds__(256) void k1_gather_cgx(
    const int* __restrict__ sent, const int* __restrict__ csent,
    const float* __restrict__ wemb, const float* __restrict__ cemb,
    const float* __restrict__ cWih_f, const float* __restrict__ cb_f,
    const float* __restrict__ cWih_b, const float* __restrict__ cb_b,
    float* __restrict__ we_g, float* __restrict__ cgx)
{
    const int tid = threadIdx.x;
    const int t0 = blockIdx.x * 16;
    __shared__ __align__(16) float ceL[16][128];
    __shared__ int sids[16], cids[16];
    if (tid < 16) sids[tid] = sent[t0 + tid];
    else if (tid < 32) cids[tid - 16] = csent[t0 + tid - 16];
    __syncthreads();
    {
        int f4 = tid;
        for (int q = 0; q < 2; ++q, f4 += 256) {
            int r = f4 >> 5, k4 = f4 & 31;
            float4 v = *(const float4*)&cemb[(size_t)cids[r] * CEDIM + k4 * 4];
            *(float4*)&ceL[r][k4 * 4] = v;
        }
    }
    {
        int f4 = tid;
        for (int q = 0; q < 8; ++q, f4 += 256) {
            int r = f4 >> 7, k4 = f4 & 127;
            float4 v = *(const float4*)&wemb[(size_t)sids[r] * EDIM + k4 * 4];
            *(float4*)&we_g[(size_t)(t0 + r) * EDIM + k4 * 4] = v;
        }
    }
    __syncthreads();
    for (int q = 0; q < 4; ++q) {
        int j = q * 256 + tid;
        int d = j >> 9, r = j & 511;
        const float* Wih = d ? cWih_b : cWih_f;
        const float* cb = d ? cb_b : cb_f;
        float b = cb[r];
        float acc[16];
#pragma unroll
        for (int tt = 0; tt < 16; ++tt) acc[tt] = b;
        for (int k4 = 0; k4 < 32; ++k4) {
            float4 wv = *(const float4*)&Wih[r * CEDIM + k4 * 4];
#pragma unroll
            for (int tt = 0; tt < 16; ++tt) {
                acc[tt] += wv.x * ceL[tt][k4 * 4 + 0] + wv.y * ceL[tt][k4 * 4 + 1]
                         + wv.z * ceL[tt][k4 * 4 + 2] + wv.w * ceL[tt][k4 * 4 + 3];
            }
        }
#pragma unroll
        for (int tt = 0; tt < 16; ++tt)
            cgx[((size_t)d * SQ + (t0 + tt)) * 512 + r] = acc[tt];
    }
}

// ---------------------------------------------------------------------------
// K2: blocks 0,1: char BiLSTM, ONE 1024-thread WG per direction. All weights
//     register-resident (64 floats/thread); sync = __syncthreads only.
//     blocks 2+: GEMM wgx = we_g . wWih[:, :512]^T + wb (1024-thread tiles)
// ---------------------------------------------------------------------------
__global__ __launch_bounds__(1024, 4) void k2_charlstm_gemm(
    const float* __restrict__ cWhh_f, const float* __restrict__ cWhh_b,
    const float* __restrict__ cgx, float* __restrict__ cho,
    const float* __restrict__ we_g,
    const float* __restrict__ wWih_f, const float* __restrict__ wb_f,
    const float* __restrict__ wWih_b, const float* __restrict__ wb_b,
    float* __restrict__ wgx)
{
    const int tid = threadIdx.x;
    __shared__ __align__(16) float At[32][68];
    __shared__ __align__(16) float Bt[32][128];
    __shared__ __align__(16) float hstC[128];
    __shared__ float partC[2][516];
    __shared__ float trC[512];

    if (blockIdx.x < 2) {
        const int dir = blockIdx.x;
        const float* Whh = dir ? cWhh_b : cWhh_f;
        const int row = tid & 511;        // gate*128 + unit
        const int half = tid >> 9;        // 0/1 -> h chunk [half*64, +64)
        const float4* wp = (const float4*)&Whh[(size_t)row * CHH + half * 64];
        float4 w0 = wp[0], w1 = wp[1], w2 = wp[2], w3 = wp[3];
        float4 w4 = wp[4], w5 = wp[5], w6 = wp[6], w7 = wp[7];
        float4 w8 = wp[8], w9 = wp[9], w10 = wp[10], w11 = wp[11];
        float4 w12 = wp[12], w13 = wp[13], w14 = wp[14], w15 = wp[15];
        PIN4(w0) PIN4(w1) PIN4(w2) PIN4(w3) PIN4(w4) PIN4(w5) PIN4(w6) PIN4(w7)
        PIN4(w8) PIN4(w9) PIN4(w10) PIN4(w11) PIN4(w12) PIN4(w13) PIN4(w14) PIN4(w15)

        const float* gxc = cgx + (size_t)dir * SQ * 512;
        float cst = 0.f;
        if (tid < 32) *(float4*)&hstC[tid * 4] = make_float4(0, 0, 0, 0);
        __syncthreads();
        for (int t = 0; t < SQ; ++t) {
            const int x = dir ? (SQ - 1 - t) : t;
            float gxv = (tid < 512) ? gxc[(size_t)x * 512 + tid] : 0.f;
            float a0 = 0.f, a1 = 0.f, a2 = 0.f, a3 = 0.f;
            const float* hc = &hstC[half * 64];
            FMA4(w0, 0)   FMA4(w1, 4)   FMA4(w2, 8)   FMA4(w3, 12)
            FMA4(w4, 16)  FMA4(w5, 20)  FMA4(w6, 24)  FMA4(w7, 28)
            FMA4(w8, 32)  FMA4(w9, 36)  FMA4(w10, 40) FMA4(w11, 44)
            FMA4(w12, 48) FMA4(w13, 52) FMA4(w14, 56) FMA4(w15, 60)
            partC[half][row] = (a0 + a1) + (a2 + a3);
            __syncthreads();
            if (tid < 512) {
                float s = partC[0][tid] + partC[1][tid] + gxv;
                const bool isg = ((tid >> 7) == 2);
                float y = sigf(isg ? (s + s) : s);     // tanh(x) = 2*sig(2x)-1
                trC[tid] = isg ? (y + y - 1.f) : y;
            }
            __syncthreads();
            if (tid < 128) {
                float iv = trC[tid], fv = trC[128 + tid];
                float gv = trC[256 + tid], ov = trC[384 + tid];
                cst = fv * cst + iv * gv;
                float ts = sigf(cst + cst);
                float h = ov * (ts + ts - 1.f);
                hstC[tid] = h;
                cho[(size_t)x * 256 + dir * CHH + tid] = h;
            }
            __syncthreads();
        }
        return;
    }
    // ---------------- GEMM (word-emb part of word gx), 1024 threads ---------
    const int tile = blockIdx.x - 2;
    const int dir = tile >> 10;
    const int rem = tile & 1023;
    const int mb = rem >> 4;   // 64-row block of t
    const int nb = rem & 15;   // 128-col block of r
    const float* Wih = dir ? wWih_b : wWih_f;
    const float* wb = dir ? wb_b : wb_f;
    float* C = wgx + (size_t)dir * SQ * 2048;
    const int tm = tid >> 6, tn = tid & 63;   // tm wave-uniform -> A broadcast
    float acc[4][2];
#pragma unroll
    for (int i = 0; i < 4; ++i) { acc[i][0] = 0.f; acc[i][1] = 0.f; }
    for (int kb = 0; kb < 16; ++kb) {
        if (tid < 512) {
            int rowm = tid >> 3, k4 = tid & 7;
            float4 v = *(const float4*)&we_g[(size_t)(mb * 64 + rowm) * EDIM + kb * 32 + k4 * 4];
            At[k4 * 4 + 0][rowm] = v.x; At[k4 * 4 + 1][rowm] = v.y;
            At[k4 * 4 + 2][rowm] = v.z; At[k4 * 4 + 3][rowm] = v.w;
        }
        {
            int rr = tid >> 3, k4 = tid & 7;
            float4 v = *(const float4*)&Wih[(size_t)(nb * 128 + rr) * 768 + kb * 32 + k4 * 4];
            Bt[k4 * 4 + 0][rr] = v.x; Bt[k4 * 4 + 1][rr] = v.y;
            Bt[k4 * 4 + 2][rr] = v.z; Bt[k4 * 4 + 3][rr] = v.w;
        }
        __syncthreads();
#pragma unroll
        for (int kk = 0; kk < 32; ++kk) {
            float4 a4 = *(const float4*)&At[kk][tm * 4];
            float2 b2 = *(const float2*)&Bt[kk][tn * 2];
            acc[0][0] += a4.x * b2.x; acc[0][1] += a4.x * b2.y;
            acc[1][0] += a4.y * b2.x; acc[1][1] += a4.y * b2.y;
            acc[2][0] += a4.z * b2.x; acc[2][1] += a4.z * b2.y;
            acc[3][0] += a4.w * b2.x; acc[3][1] += a4.w * b2.y;
        }
        __syncthreads();
    }
    float2 wbv = *(const float2*)&wb[nb * 128 + tn * 2];
#pragma unroll
    for (int i = 0; i < 4; ++i) {
        float2 o;
        o.x = acc[i][0] + wbv.x; o.y = acc[i][1] + wbv.y;
        *(float2*)&C[(size_t)(mb * 64 + tm * 4 + i) * 2048 + nb * 128 + tn * 2] = o;
    }
}

// ---------------------------------------------------------------------------
// K3: wgx += char_out . wWih[:,512:768]^T
// ---------------------------------------------------------------------------
__global__ __launch_bounds__(512, 2) void k3_gemm_char(
    const float* __restrict__ cho,
    const float* __restrict__ wWih_f, const float* __restrict__ wWih_b,
    float* __restrict__ wgx)
{
    const int tid = threadIdx.x;
    const int tile = blockIdx.x;
    const int dir = tile >> 10;
    const int rem = tile & 1023;
    const int mb = rem >> 4, nb = rem & 15;
    const float* Wih = dir ? wWih_b : wWih_f;
    float* C = wgx + (size_t)dir * SQ * 2048;
    __shared__ __align__(16) float At[32][68];
    __shared__ __align__(16) float Bt[32][128];
    const int tm = tid >> 5, tn = tid & 31;
    float acc[4][4];
#pragma unroll
    for (int i = 0; i < 4; ++i)
#pragma unroll
        for (int jj = 0; jj < 4; ++jj) acc[i][jj] = 0.f;
    for (int kb = 0; kb < 8; ++kb) {
        {
            int rowm = tid >> 3, k4 = tid & 7;
            float4 v = *(const float4*)&cho[(size_t)(mb * 64 + rowm) * 256 + kb * 32 + k4 * 4];
            At[k4 * 4 + 0][rowm] = v.x; At[k4 * 4 + 1][rowm] = v.y;
            At[k4 * 4 + 2][rowm] = v.z; At[k4 * 4 + 3][rowm] = v.w;
        }
#pragma unroll
        for (int q = 0; q < 2; ++q) {
            int f4 = q * 512 + tid;
            int rr = f4 >> 3, k4 = f4 & 7;
            float4 v = *(const float4*)&Wih[(size_t)(nb * 128 + rr) * 768 + 512 + kb * 32 + k4 * 4];
            Bt[k4 * 4 + 0][rr] = v.x; Bt[k4 * 4 + 1][rr] = v.y;
            Bt[k4 * 4 + 2][rr] = v.z; Bt[k4 * 4 + 3][rr] = v.w;
        }
        __syncthreads();
#pragma unroll
        for (int kk = 0; kk < 32; ++kk) {
            float4 a4 = *(const float4*)&At[kk][tm * 4];
            float4 b4 = *(const float4*)&Bt[kk][tn * 4];
            acc[0][0] += a4.x * b4.x; acc[0][1] += a4.x * b4.y; acc[0][2] += a4.x * b4.z; acc[0][3] += a4.x * b4.w;
            acc[1][0] += a4.y * b4.x; acc[1][1] += a4.y * b4.y; acc[1][2] += a4.y * b4.z; acc[1][3] += a4.y * b4.w;
            acc[2][0] += a4.z * b4.x; acc[2][1] += a4.z * b4.y; acc[2][2] += a4.z * b4.z; acc[2][3] += a4.z * b4.w;
            acc[3][0] += a4.w * b4.x; acc[3][1] += a4.w * b4.y; acc[3][2] += a4.w * b4.z; acc[3][3] += a4.w * b4.w;
        }
        __syncthreads();
    }
#pragma unroll
    for (int i = 0; i < 4; ++i) {
        float* cp = &C[(size_t)(mb * 64 + tm * 4 + i) * 2048 + nb * 128 + tn * 4];
        float4 o = *(float4*)cp;
        o.x += acc[i][0]; o.y += acc[i][1]; o.z += acc[i][2]; o.w += acc[i][3];
        *(float4*)cp = o;
    }
}

// ---------------------------------------------------------------------------
// K4: word BiLSTM. 32 WGs/direction x 1024 threads, tagged-pair h exchange
//     (round-10 recipe). Wave-parallel epilogue: 64-lane gate sums + shfl
//     gather + distributed transcendentals (one sigf per lane).
// ---------------------------------------------------------------------------
__global__ __launch_bounds__(1024, 4) void k4_word_lstm(
    const float* __restrict__ wWhh_f, const float* __restrict__ wWhh_b,
    const float* __restrict__ wgx, float* __restrict__ lstm, ull* __restrict__ pairs)
{
    const int res = blockIdx.x & 7;
    if (res > 1) return;
    const int dir = res;
    const int wid = blockIdx.x >> 3;      // 0..31
    const int tid = threadIdx.x;
    const int k = tid >> 6;               // h-chunk = wave id (0..15)
    const int r = tid & 63;               // g*16+u
    const int g = r >> 4, u = r & 15;
    const float* Whh = dir ? wWhh_b : wWhh_f;
    const int G = g * WH + wid * 16 + u;
    const float4* wp = (const float4*)&Whh[(size_t)G * WH + k * 32];
    float4 w0 = wp[0], w1 = wp[1], w2 = wp[2], w3 = wp[3];
    float4 w4 = wp[4], w5 = wp[5], w6 = wp[6], w7 = wp[7];
    PIN4(w0) PIN4(w1) PIN4(w2) PIN4(w3) PIN4(w4) PIN4(w5) PIN4(w6) PIN4(w7)

    __shared__ __align__(16) float hst[512];
    __shared__ float part[16][65];

    ull* wpf = pairs;            // [2][2][512] fast
    ull* wpm = pairs + 2048;     // mirror
    const float* gx = wgx + (size_t)dir * SQ * 2048;
    float cst = 0.f;
    int useFast = 1, alive = 1;
    for (int t = 0; t < SQ; ++t) {
        const int x = dir ? (SQ - 1 - t) : t;
        float gxv = 0.f;
        if (tid < 64)
            gxv = gx[(size_t)x * 2048 + (size_t)(tid >> 4) * 512 + wid * 16 + (tid & 15)];
        if (t == 0) {
            if (tid < 128) *(float4*)&hst[tid * 4] = make_float4(0, 0, 0, 0);
        } else if (tid < 64) {            // wave0: poll 8 pairs/lane + stage h
            const size_t boff = ((size_t)((t - 1) & 1) * 2 + dir) * 512 + tid * 8;
            const ull* pf = wpf + boff;
            const ull* pm = wpm + boff;
            ull q0 = 0, q1 = 0, q2 = 0, q3 = 0, q4 = 0, q5 = 0, q6 = 0, q7 = 0;
            int spins = 0;
            while (alive) {
                if (useFast) {
                    ld8x_sc0(pf, q0, q1, q2, q3, q4, q5, q6, q7);
                } else {
                    q0 = ld_mir(pm + 0); q1 = ld_mir(pm + 1);
                    q2 = ld_mir(pm + 2); q3 = ld_mir(pm + 3);
                    q4 = ld_mir(pm + 4); q5 = ld_mir(pm + 5);
                    q6 = ld_mir(pm + 6); q7 = ld_mir(pm + 7);
                }
                unsigned tm = umin2(umin2(umin2((unsigned)(q0 >> 32), (unsigned)(q1 >> 32)),
                                          umin2((unsigned)(q2 >> 32), (unsigned)(q3 >> 32))),
                                    umin2(umin2((unsigned)(q4 >> 32), (unsigned)(q5 >> 32)),
                                          umin2((unsigned)(q6 >> 32), (unsigned)(q7 >> 32))));
                if (__all(tm >= (unsigned)t)) break;
                ++spins;
                if (useFast && spins > 2048) { useFast = 0; spins = 0; }
                if (!useFast && spins > (1 << 20)) alive = 0;
                __builtin_amdgcn_s_sleep(1);
            }
            float* hd = &hst[tid * 8];
            hd[0] = __uint_as_float((unsigned)q0); hd[1] = __uint_as_float((unsigned)q1);
            hd[2] = __uint_as_float((unsigned)q2); hd[3] = __uint_as_float((unsigned)q3);
            hd[4] = __uint_as_float((unsigned)q4); hd[5] = __uint_as_float((unsigned)q5);
            hd[6] = __uint_as_float((unsigned)q6); hd[7] = __uint_as_float((unsigned)q7);
        }
        __syncthreads();
        float a0 = 0.f, a1 = 0.f, a2 = 0.f, a3 = 0.f;
        const float* hc = &hst[k * 32];
        FMA4(w0, 0)  FMA4(w1, 4)  FMA4(w2, 8)  FMA4(w3, 12)
        FMA4(w4, 16) FMA4(w5, 20) FMA4(w6, 24) FMA4(w7, 28)
        part[k][r] = (a0 + a1) + (a2 + a3);
        __syncthreads();
        if (tid < 64) {
            float s = gxv;
#pragma unroll
            for (int kk = 0; kk < 16; ++kk) s += part[kk][tid];
            const bool isg = ((tid >> 4) == 2);
            float y = sigf(isg ? (s + s) : s);     // tanh(x) = 2*sig(2x)-1
            float val = isg ? (y + y - 1.f) : y;
            float fv = __shfl(val, 16 + (tid & 15));
            float gv = __shfl(val, 32 + (tid & 15));
            float ov = __shfl(val, 48 + (tid & 15));
            if (tid < 16) {
                cst = fv * cst + val * gv;         // val = i-gate (lanes 0..15)
                float ts = sigf(cst + cst);
                float h = ov * (ts + ts - 1.f);
                const int unit = wid * 16 + tid;
                lstm[(size_t)x * 1024 + dir * WH + unit] = h;
                ull q = ((ull)(unsigned)(t + 1) << 32) | (ull)__float_as_uint(h);
                const size_t poff = ((size_t)(t & 1) * 2 + dir) * 512 + unit;
                st_plain8(wpf + poff, q);
                st_mir(wpm + poff, q);
            }
        }
    }
}

// ---------------------------------------------------------------------------
// K5: emissions = lstm_out @ W_tag^T + b_tag
// ---------------------------------------------------------------------------
__global__ __launch_bounds__(64) void k5_emis(
    const float* __restrict__ lstm, const float* __restrict__ Wtag,
    const float* __restrict__ btag, float* __restrict__ emis)
{
    const int t = blockIdx.x, tid = threadIdx.x;
    __shared__ __align__(16) float rowL[1024];
#pragma unroll
    for (int q = 0; q < 4; ++q) {
        int f4 = q * 64 + tid;
        *(float4*)&rowL[f4 * 4] = *(const float4*)&lstm[(size_t)t * 1024 + f4 * 4];
    }
    __syncthreads();
    if (tid < NT) {
        float a0 = 0.f, a1 = 0.f, a2 = 0.f, a3 = 0.f;
        const float* wr = Wtag + (size_t)tid * 1024;
        for (int k4 = 0; k4 < 256; ++k4) {
            float4 wv = *(const float4*)&wr[k4 * 4];
            a0 += wv.x * rowL[k4 * 4 + 0];
            a1 += wv.y * rowL[k4 * 4 + 1];
            a2 += wv.z * rowL[k4 * 4 + 2];
            a3 += wv.w * rowL[k4 * 4 + 3];
        }
        emis[(size_t)t * NT + tid] = btag[tid] + (a0 + a1) + (a2 + a3);
    }
}

// ---------------------------------------------------------------------------
// K6a: Viterbi forward (sequential)
// ---------------------------------------------------------------------------
__global__ __launch_bounds__(256) void k6a_viterbi(
    const float* __restrict__ emis, const float* __restrict__ start_t,
    const float* __restrict__ end_t, const float* __restrict__ trans,
    unsigned char* __restrict__ bpb, int* __restrict__ last)
{
    const int tid = threadIdx.x;
    const int g = tid >> 6, c = tid & 63;
    __shared__ float sc[64];
    __shared__ float pbest[4][64];
    __shared__ int pbp[4][64];
    const int p0 = g * 13;
    float tr[13];
#pragma unroll
    for (int i = 0; i < 13; ++i) {
        int p = p0 + i;
        tr[i] = (c < NT && p < NT) ? trans[p * NT + c] : -1e30f;
    }
    if (tid < 64) sc[tid] = (tid < NT) ? (start_t[tid] + emis[tid]) : -1e30f;
    __syncthreads();
    for (int t = 1; t < SQ; ++t) {
        float best = -1e30f; int bp = 0;
#pragma unroll
        for (int i = 0; i < 13; ++i) {
            float v = sc[p0 + i] + tr[i];
            if (v > best) { best = v; bp = p0 + i; }
        }
        pbest[g][c] = best; pbp[g][c] = bp;
        __syncthreads();
        if (tid < NT) {
            float b = pbest[0][tid]; int bb = pbp[0][tid];
#pragma unroll
            for (int gg = 1; gg < 4; ++gg) {
                float v = pbest[gg][tid];
                if (v > b) { b = v; bb = pbp[gg][tid]; }
            }
            bpb[(size_t)t * NT + tid] = (unsigned char)bb;
            sc[tid] = b + emis[(size_t)t * NT + tid];
        }
        __syncthreads();
    }
    if (tid == 0) {
        float b = -1e30f; int bi = 0;
        for (int cc = 0; cc < NT; ++cc) {
            float v = sc[cc] + end_t[cc];
            if (v > b) { b = v; bi = cc; }
        }
        *last = bi;
    }
}

// K6b: per-chunk end-tag -> end-of-previous-chunk-tag maps
__global__ __launch_bounds__(64) void k6b_maps(
    const unsigned char* __restrict__ bpb, int* __restrict__ map_)
{
    const int k = blockIdx.x;
    const int e = threadIdx.x;
    if (k == 0 || e >= NT) return;
    int tag = e;
    for (int i = 63; i >= 0; --i) {
        int t = k * 64 + i;
        tag = bpb[(size_t)t * NT + tag];
    }
    map_[k * NT + e] = tag;
}

// K6c: stitch chunk boundary tags, emit path
__global__ __launch_bounds__(64) void k6c_backtrack(
    const unsigned char* __restrict__ bpb, const int* __restrict__ map_,
    const int* __restrict__ last, int* __restrict__ path)
{
    __shared__ int B[64];
    if (threadIdx.x == 0) {
        int tag = *last;
        B[63] = tag;
        for (int k = 63; k >= 1; --k) {
            tag = map_[k * NT + tag];
            B[k - 1] = tag;
        }
    }
    __syncthreads();
    const int k = threadIdx.x;
    int tag = B[k];
    for (int i = 63; i >= 0; --i) {
        int t = k * 64 + i;
        path[t] = tag;
        if (t >= 1) tag = bpb[(size_t)t * NT + tag];
    }
}

// ---------------------------------------------------------------------------
extern "C" void kernel_launch(void* const* d_in, const int* in_sizes, int n_in,
                              void* d_out, int out_size, void* d_ws, size_t ws_size,
                              hipStream_t stream)
{
    const int* sent = (const int*)d_in[0];
    const int* csent = (const int*)d_in[1];
    const float* wemb = (const float*)d_in[2];
    const float* cemb = (const float*)d_in[3];
    const float* cWih_f = (const float*)d_in[4];
    const float* cWhh_f = (const float*)d_in[5];
    const float* cb_f = (const float*)d_in[6];
    const float* cWih_b = (const float*)d_in[7];
    const float* cWhh_b = (const float*)d_in[8];
    const float* cb_b = (const float*)d_in[9];
    const float* wWih_f = (const float*)d_in[10];
    const float* wWhh_f = (const float*)d_in[11];
    const float* wb_f = (const float*)d_in[12];
    const float* wWih_b = (const float*)d_in[13];
    const float* wWhh_b = (const float*)d_in[14];
    const float* wb_b = (const float*)d_in[15];
    const float* Wtag = (const float*)d_in[16];
    const float* btag = (const float*)d_in[17];
    const float* start_t = (const float*)d_in[18];
    const float* end_t = (const float*)d_in[19];
    const float* trans = (const float*)d_in[20];
    int* path = (int*)d_out;

    float* ws = (float*)d_ws;
    float* we_g = ws;                                   // SQ*EDIM
    float* cgx  = we_g + (size_t)SQ * EDIM;             // 2*SQ*512
    float* cho  = cgx + (size_t)2 * SQ * 512;           // SQ*256
    float* wgx  = cho + (size_t)SQ * 256;               // 2*SQ*2048
    float* lstm = wgx + (size_t)2 * SQ * 2048;          // SQ*1024
    float* emis = lstm + (size_t)SQ * 1024;             // SQ*NT
    ull* pairs  = (ull*)(emis + (size_t)SQ * NT);       // 5120 ulongs (40KB)
    int* map_   = (int*)(pairs + 5120);                 // 64*NT
    int* lastp  = map_ + 64 * NT;                       // 1 (+pad)
    unsigned char* bpb = (unsigned char*)(lastp + 4);   // SQ*NT bytes

    (void)hipMemsetAsync(pairs, 0, 5120 * sizeof(ull), stream);

    k1_gather_cgx<<<SQ / 16, 256, 0, stream>>>(sent, csent, wemb, cemb,
                                               cWih_f, cb_f, cWih_b, cb_b, we_g, cgx);
    k2_charlstm_gemm<<<2 + 2048, 1024, 0, stream>>>(cWhh_f, cWhh_b, cgx, cho, we_g,
                                                    wWih_f, wb_f, wWih_b, wb_b, wgx);
    k3_gemm_char<<<2048, 512, 0, stream>>>(cho, wWih_f, wWih_b, wgx);
    k4_word_lstm<<<256, 1024, 0, stream>>>(wWhh_f, wWhh_b, wgx, lstm, pairs);
    k5_emis<<<SQ, 64, 0, stream>>>(lstm, Wtag, btag, emis);
    k6a_viterbi<<<1, 256, 0, stream>>>(emis, start_t, end_t, trans, bpb, lastp);
    k6b_maps<<<64, 64, 0, stream>>>(bpb, map_);
    k6c_backtrack<<<1, 64, 0, stream>>>(bpb, map_, lastp, path);
}